// Round 5
// baseline (4423.931 us; speedup 1.0000x reference)
//
#include <hip/hip_runtime.h>
#include <hip/hip_bf16.h>

#define BATCH   4
#define SEQ     2048
#define DMODEL  1024
#define NHEADS  16
#define DHEAD   64
#define MROWS   (BATCH*SEQ)        // 8192
#define QKV_N   (3*DMODEL)         // 3072
#define NEG_BIG (-1.0e30f)
// ws requirement: K/V as bf16 [8192, 2048] = 33,554,432 bytes (proven available)
#define WS_NEED ((size_t)MROWS * 2*DMODEL * sizeof(__hip_bfloat16))

using bf16 = __hip_bfloat16;

__device__ __forceinline__ float bf2f_bits(unsigned short u) {
    return __uint_as_float(((unsigned)u) << 16);
}

// ---------------------------------------------------------------------------
// Tiled GEMM with bias: C[M,N](ldc) = A[M,K](lda) @ B[K,N](ldb) + bias[N]
// A,B,bias fp32. C fp32 or bf16 (compile-time). f32 accumulate.
// M,N multiples of 128; K multiple of 16; element offsets 4-aligned (16B).
// ---------------------------------------------------------------------------
#define BM 128
#define BN 128
#define BKK 16

__device__ __forceinline__ void loadf8(const float* p, float* d) {
    const float4 a = *(const float4*)p;
    const float4 b = *(const float4*)(p + 4);
    d[0]=a.x; d[1]=a.y; d[2]=a.z; d[3]=a.w;
    d[4]=b.x; d[5]=b.y; d[6]=b.z; d[7]=b.w;
}

template<bool OUT_BF16>
__global__ __launch_bounds__(256) void gemm_bias(
    const float* __restrict__ A, const float* __restrict__ B,
    const float* __restrict__ bias, void* __restrict__ Cv,
    int N, int K, int lda, int ldb, int ldc)
{
    __shared__ float As[BKK][BM];   // [k][m]
    __shared__ float Bs[BKK][BN];   // [k][n]

    const int tid = threadIdx.x;
    const int bm = blockIdx.y, bn = blockIdx.x;
    const int tx = tid & 15;
    const int ty = tid >> 4;

    const int aRow = tid >> 1;            // 0..127
    const int aCol = (tid & 1) * 8;       // 0 or 8
    const int bRow = tid >> 4;            // 0..15
    const int bCol = (tid & 15) * 8;      // 0..120

    const float* Aptr = A + (size_t)(bm*BM + aRow)*lda + aCol;
    const float* Bptr = B + (size_t)bRow*ldb + (size_t)bn*BN + bCol;

    float acc[8][8];
#pragma unroll
    for (int i = 0; i < 8; i++)
#pragma unroll
        for (int j = 0; j < 8; j++) acc[i][j] = 0.f;

    for (int k0 = 0; k0 < K; k0 += BKK) {
        float av[8], bv8[8];
        loadf8(Aptr + k0, av);
        loadf8(Bptr + (size_t)k0*ldb, bv8);

        __syncthreads();   // previous iteration's LDS reads complete
#pragma unroll
        for (int i = 0; i < 8; i++) As[aCol + i][aRow] = av[i];
#pragma unroll
        for (int i = 0; i < 8; i++) Bs[bRow][bCol + i] = bv8[i];
        __syncthreads();

#pragma unroll
        for (int kk = 0; kk < BKK; kk++) {
            float rm[8], rn[8];
#pragma unroll
            for (int i = 0; i < 8; i++) rm[i] = As[kk][ty*8 + i];
#pragma unroll
            for (int i = 0; i < 8; i++) rn[i] = Bs[kk][tx*8 + i];
#pragma unroll
            for (int i = 0; i < 8; i++)
#pragma unroll
                for (int j = 0; j < 8; j++)
                    acc[i][j] += rm[i] * rn[j];
        }
    }

    const int rowG0 = bm*BM + ty*8;
    const int colG0 = bn*BN + tx*8;
    float bv[8];
#pragma unroll
    for (int j = 0; j < 8; j++) bv[j] = bias[colG0 + j];

#pragma unroll
    for (int i = 0; i < 8; i++) {
        if (OUT_BF16) {
            union { uint4 u4; bf16 b[8]; } o;
#pragma unroll
            for (int j = 0; j < 8; j++) o.b[j] = __float2bfloat16(acc[i][j] + bv[j]);
            *(uint4*)((bf16*)Cv + (size_t)(rowG0 + i)*ldc + colG0) = o.u4;
        } else {
            float* Crow = (float*)Cv + (size_t)(rowG0 + i)*ldc + colG0;
            float4 o0, o1;
            o0.x = acc[i][0]+bv[0]; o0.y = acc[i][1]+bv[1];
            o0.z = acc[i][2]+bv[2]; o0.w = acc[i][3]+bv[3];
            o1.x = acc[i][4]+bv[4]; o1.y = acc[i][5]+bv[5];
            o1.z = acc[i][6]+bv[6]; o1.w = acc[i][7]+bv[7];
            *(float4*)Crow = o0;
            *(float4*)(Crow + 4) = o1;
        }
    }
}

// ---------------------------------------------------------------------------
// Causal attention. Q fp32 [t*ldq + h*64 + d] (in d_out), K/V bf16
// [t*ldkv + h*64 + d] (in ws, K cols 0..1023, V cols 1024..2047),
// O fp32 in-place over Q (each thread reads only the element it writes;
// distinct (q,h) pairs touch distinct addresses -> no cross-block overlap).
// One wave per query row; 4 rows/block share 64-key K/V LDS tiles;
// online softmax with big-negative masking (no infinities).
// ---------------------------------------------------------------------------
__global__ __launch_bounds__(256) void attn_causal(
    const float* Qg, const bf16* __restrict__ Kg,
    const bf16* __restrict__ Vg, float* Og,
    int ldq, int ldkv, int ldo)
{
    __shared__ float Kt[64][65];
    __shared__ float Vt[64][65];
    __shared__ float Qs[4][64];

    const int b    = blockIdx.z;
    const int h    = blockIdx.y;
    const int qb   = blockIdx.x;
    const int w    = threadIdx.x >> 6;
    const int lane = threadIdx.x & 63;
    const int q    = qb*4 + w;

    Qs[w][lane] = Qg[(size_t)(b*SEQ + q)*ldq + h*DHEAD + lane];

    float o = 0.f, m = NEG_BIG, lsum = 0.f;
    const int nTiles = (qb*4 + 3)/64 + 1;   // block-uniform

    for (int kt = 0; kt < nTiles; kt++) {
        __syncthreads();
        for (int idx = threadIdx.x; idx < 64*8; idx += 256) {
            const int r = idx >> 3, c8 = (idx & 7)*8;
            const size_t base = (size_t)(b*SEQ + kt*64 + r)*ldkv + h*DHEAD + c8;
            union { uint4 u4; unsigned short us[8]; } kk, vv;
            kk.u4 = *(const uint4*)(Kg + base);
            vv.u4 = *(const uint4*)(Vg + base);
#pragma unroll
            for (int i = 0; i < 8; i++) {
                Kt[r][c8+i] = bf2f_bits(kk.us[i]);
                Vt[r][c8+i] = bf2f_bits(vv.us[i]);
            }
        }
        __syncthreads();

        const int key = kt*64 + lane;
        float s = 0.f;
#pragma unroll
        for (int d = 0; d < 64; d++) s += Qs[w][d] * Kt[lane][d];
        s = (key <= q) ? s * 0.125f : NEG_BIG;   // scale = 1/sqrt(64)

        float tmax = s;
#pragma unroll
        for (int off = 32; off; off >>= 1) tmax = fmaxf(tmax, __shfl_xor(tmax, off));
        const float mnew  = fmaxf(m, tmax);
        const float alpha = __expf(m - mnew);
        const float p     = __expf(s - mnew);    // masked lanes -> 0

        float psum = p;
#pragma unroll
        for (int off = 32; off; off >>= 1) psum += __shfl_xor(psum, off);
        lsum = lsum*alpha + psum;
        o   *= alpha;
#pragma unroll
        for (int j = 0; j < 64; j++) {
            const float pj = __shfl(p, j);
            o += pj * Vt[j][lane];
        }
        m = mnew;
    }

    Og[(size_t)(b*SEQ + q)*ldo + h*DHEAD + lane] = o / fmaxf(lsum, 1e-20f);
}

// Diagnostic: encode ws_size (MB) into the output if ws is too small.
__global__ void diag_fill(float* out, int n, float val) {
    int i = blockIdx.x*blockDim.x + threadIdx.x;
    if (i < n) out[i] = val;
}

// ---------------------------------------------------------------------------
extern "C" void kernel_launch(void* const* d_in, const int* in_sizes, int n_in,
                              void* d_out, int out_size, void* d_ws, size_t ws_size,
                              hipStream_t stream) {
    const float* x     = (const float*)d_in[0]; // [4,2048,1024]
    const float* W_qkv = (const float*)d_in[1]; // [1024,3072]
    const float* b_qkv = (const float*)d_in[2]; // [3072]
    const float* W_out = (const float*)d_in[3]; // [1024,1024]
    const float* b_out = (const float*)d_in[4]; // [1024]
    float* out = (float*)d_out;                 // [4,2048,1024] fp32
    bf16*  kv  = (bf16*)d_ws;                   // K/V bf16 [8192, 2048]

    if (ws_size < WS_NEED) {
        const float val = 100.f + (float)(ws_size >> 20);
        diag_fill<<<(out_size + 255)/256, 256, 0, stream>>>(out, out_size, val);
        return;
    }

    // 1) Q projection -> d_out fp32 [8192,1024]
    {
        dim3 g(DMODEL/BN, MROWS/BM);
        gemm_bias<false><<<g, 256, 0, stream>>>(x, W_qkv, b_qkv, out,
                                                DMODEL, DMODEL, DMODEL, QKV_N, DMODEL);
    }
    // 2) K,V projection -> ws bf16 [8192,2048] (W_qkv cols 1024..3071)
    {
        dim3 g(2*DMODEL/BN, MROWS/BM);
        gemm_bias<true><<<g, 256, 0, stream>>>(x, W_qkv + DMODEL, b_qkv + DMODEL, kv,
                                               2*DMODEL, DMODEL, DMODEL, QKV_N, 2*DMODEL);
    }
    // 3) causal attention, in-place over Q in d_out
    {
        dim3 g(SEQ/4, NHEADS, BATCH);
        attn_causal<<<g, 256, 0, stream>>>(out, kv, kv + DMODEL, out,
                                           DMODEL, 2*DMODEL, DMODEL);
    }
    // 4) output projection -> ws fp32 (K/V dead; 33.5 MB fits), D2D back
    {
        float* proj = (float*)d_ws;
        dim3 g(DMODEL/BN, MROWS/BM);
        gemm_bias<false><<<g, 256, 0, stream>>>(out, W_out, b_out, proj,
                                                DMODEL, DMODEL, DMODEL, DMODEL, DMODEL);
        hipMemcpyAsync(out, proj, (size_t)MROWS*DMODEL*sizeof(float),
                       hipMemcpyDeviceToDevice, stream);
    }
}

// Round 6
// 1104.746 us; speedup vs baseline: 4.0045x; 4.0045x over previous
//
#include <hip/hip_runtime.h>
#include <hip/hip_bf16.h>

#define BATCH   4
#define SEQ     2048
#define DMODEL  1024
#define NHEADS  16
#define DHEAD   64
#define MROWS   (BATCH*SEQ)        // 8192
#define QKV_N   (3*DMODEL)         // 3072
#define NEG_BIG (-1.0e30f)
#define WS_NEED ((size_t)MROWS * 2*DMODEL * sizeof(__hip_bfloat16))  // 33,554,432

using bf16 = __hip_bfloat16;
typedef __attribute__((ext_vector_type(8))) short short8;   // 8 bf16 = 4 VGPR
typedef __attribute__((ext_vector_type(4))) float floatx4;

__device__ __forceinline__ float bf2f_bits(unsigned short u) {
    return __uint_as_float(((unsigned)u) << 16);
}
__device__ __forceinline__ unsigned short f2bf_rne(float f) {
    union { bf16 b; unsigned short u; } t;
    t.b = __float2bfloat16(f);
    return t.u;
}

// ---------------------------------------------------------------------------
// Tiled GEMM with bias: C[M,N](ldc) = A[M,K](lda) @ B[K,N](ldb) + bias[N]
// A fp32 or bf16 (template), B/bias fp32, C fp32 or bf16 (template).
// f32 accumulate. M,N mult of 128; K mult of 16; offsets 16B-aligned.
// ---------------------------------------------------------------------------
#define BM 128
#define BN 128
#define BKK 16

__device__ __forceinline__ void loadf8(const float* p, float* d) {
    const float4 a = *(const float4*)p;
    const float4 b = *(const float4*)(p + 4);
    d[0]=a.x; d[1]=a.y; d[2]=a.z; d[3]=a.w;
    d[4]=b.x; d[5]=b.y; d[6]=b.z; d[7]=b.w;
}
__device__ __forceinline__ void loadb8(const bf16* p, float* d) {
    union { uint4 u4; unsigned short us[8]; } t;
    t.u4 = *(const uint4*)p;
#pragma unroll
    for (int i = 0; i < 8; i++) d[i] = bf2f_bits(t.us[i]);
}

template<bool A_BF16, bool OUT_BF16>
__global__ __launch_bounds__(256) void gemm_bias(
    const void* __restrict__ Av, const float* __restrict__ B,
    const float* __restrict__ bias, void* __restrict__ Cv,
    int N, int K, int lda, int ldb, int ldc)
{
    __shared__ float As[BKK][BM];
    __shared__ float Bs[BKK][BN];

    const int tid = threadIdx.x;
    const int bm = blockIdx.y, bn = blockIdx.x;
    const int tx = tid & 15;
    const int ty = tid >> 4;

    const int aRow = tid >> 1;
    const int aCol = (tid & 1) * 8;
    const int bRow = tid >> 4;
    const int bCol = (tid & 15) * 8;

    const size_t aBase = (size_t)(bm*BM + aRow)*lda + aCol;
    const float* Bptr = B + (size_t)bRow*ldb + (size_t)bn*BN + bCol;

    float acc[8][8];
#pragma unroll
    for (int i = 0; i < 8; i++)
#pragma unroll
        for (int j = 0; j < 8; j++) acc[i][j] = 0.f;

    for (int k0 = 0; k0 < K; k0 += BKK) {
        float av[8], bv8[8];
        if (A_BF16) loadb8((const bf16*)Av + aBase + k0, av);
        else        loadf8((const float*)Av + aBase + k0, av);
        loadf8(Bptr + (size_t)k0*ldb, bv8);

        __syncthreads();
#pragma unroll
        for (int i = 0; i < 8; i++) As[aCol + i][aRow] = av[i];
#pragma unroll
        for (int i = 0; i < 8; i++) Bs[bRow][bCol + i] = bv8[i];
        __syncthreads();

#pragma unroll
        for (int kk = 0; kk < BKK; kk++) {
            float rm[8], rn[8];
#pragma unroll
            for (int i = 0; i < 8; i++) rm[i] = As[kk][ty*8 + i];
#pragma unroll
            for (int i = 0; i < 8; i++) rn[i] = Bs[kk][tx*8 + i];
#pragma unroll
            for (int i = 0; i < 8; i++)
#pragma unroll
                for (int j = 0; j < 8; j++)
                    acc[i][j] += rm[i] * rn[j];
        }
    }

    const int rowG0 = bm*BM + ty*8;
    const int colG0 = bn*BN + tx*8;
    float bv[8];
#pragma unroll
    for (int j = 0; j < 8; j++) bv[j] = bias[colG0 + j];

#pragma unroll
    for (int i = 0; i < 8; i++) {
        if (OUT_BF16) {
            union { uint4 u4; bf16 b[8]; } o;
#pragma unroll
            for (int j = 0; j < 8; j++) o.b[j] = __float2bfloat16(acc[i][j] + bv[j]);
            *(uint4*)((bf16*)Cv + (size_t)(rowG0 + i)*ldc + colG0) = o.u4;
        } else {
            float* Crow = (float*)Cv + (size_t)(rowG0 + i)*ldc + colG0;
            float4 o0, o1;
            o0.x = acc[i][0]+bv[0]; o0.y = acc[i][1]+bv[1];
            o0.z = acc[i][2]+bv[2]; o0.w = acc[i][3]+bv[3];
            o1.x = acc[i][4]+bv[4]; o1.y = acc[i][5]+bv[5];
            o1.z = acc[i][6]+bv[6]; o1.w = acc[i][7]+bv[7];
            *(float4*)Crow = o0;
            *(float4*)(Crow + 4) = o1;
        }
    }
}

// ---------------------------------------------------------------------------
// V transpose: V[b*T+t][h*64+d] -> VT[((b*16+h)*64+d)*2048 + t]
// ---------------------------------------------------------------------------
__global__ __launch_bounds__(256) void transpose_v(
    const bf16* __restrict__ V, bf16* __restrict__ VT)
{
    __shared__ unsigned short T[64][65];
    const int b = blockIdx.z, hh = blockIdx.y;
    const int t0 = blockIdx.x * 64;
    const int tid = threadIdx.x;
    const int r = tid >> 2, c0 = (tid & 3) * 16;

#pragma unroll
    for (int it = 0; it < 2; ++it) {
        const int c = c0 + it*8;
        union { uint4 u4; unsigned short us[8]; } v;
        v.u4 = *(const uint4*)(V + (size_t)(b*SEQ + t0 + r)*DMODEL + hh*DHEAD + c);
#pragma unroll
        for (int j = 0; j < 8; j++) T[r][c+j] = v.us[j];
    }
    __syncthreads();
    const int d = tid >> 2, tc0 = (tid & 3) * 16;
#pragma unroll
    for (int it = 0; it < 2; ++it) {
        const int tc = tc0 + it*8;
        union { uint4 u4; unsigned short us[8]; } u;
#pragma unroll
        for (int j = 0; j < 8; j++) u.us[j] = T[tc+j][d];
        *(uint4*)(VT + (size_t)((b*NHEADS + hh)*DHEAD + d)*SEQ + t0 + tc) = u.u4;
    }
}

// ---------------------------------------------------------------------------
// MFMA flash attention (bf16, causal). Per block: 64 queries of one (b,h);
// 4 waves x 16 query rows. K-tiles of 64 keys staged in LDS (K[key][d],
// VT[d][key], both 16B-vector copies). S = QK^T via 16x16x32 MFMA; online
// softmax in registers (C-layout rows); P -> LDS (bf16) -> A-frags; PV MFMA.
// Layouts (HW-verified): C/D col=lane&15,row=quad*4+reg; A[m=lane&15][k=quad*8+j].
// ---------------------------------------------------------------------------
__global__ __launch_bounds__(256) void attn_mfma(
    const bf16* __restrict__ Qg, const bf16* __restrict__ Kg,
    const bf16* __restrict__ VTg, bf16* __restrict__ Og)
{
    __shared__ alignas(16) unsigned short Kt[64][72];   // [key][d]
    __shared__ alignas(16) unsigned short Vt[64][72];   // [d][key]
    __shared__ alignas(16) unsigned short Ps[4][16][72];// [wave][q][key]

    const int b = blockIdx.z, h = blockIdx.y, qt = blockIdx.x;
    const int q0 = qt * 64;
    const int tid = threadIdx.x;
    const int w = tid >> 6, lane = tid & 63;
    const int m16 = lane & 15, quad = lane >> 4;
    const int qw0 = q0 + w*16;

    // Q A-fragments (2 chunks of k=32)
    short8 qf[2];
    {
        const size_t base = (size_t)(b*SEQ + qw0 + m16)*DMODEL + h*DHEAD + quad*8;
        qf[0] = *(const short8*)(Qg + base);
        qf[1] = *(const short8*)(Qg + base + 32);
    }

    floatx4 of[4];
    float mrow[4], lrow[4];
#pragma unroll
    for (int nt = 0; nt < 4; nt++) { of[nt][0]=0.f; of[nt][1]=0.f; of[nt][2]=0.f; of[nt][3]=0.f; }
#pragma unroll
    for (int r = 0; r < 4; r++) { mrow[r] = NEG_BIG; lrow[r] = 0.f; }

    const int sr  = tid >> 2;          // staging row 0..63
    const int sc0 = (tid & 3) * 8;     // staging col 0..24

    const int nkt = qt + 1;
    for (int kt = 0; kt < nkt; ++kt) {
        const int k0 = kt * 64;
        __syncthreads();
        // stage K-tile and VT-tile (vectorized, no transpose needed)
        {
            const bf16* kp = Kg  + (size_t)(b*SEQ + k0 + sr)*DMODEL + h*DHEAD + sc0;
            const bf16* vp = VTg + (size_t)((b*NHEADS + h)*DHEAD + sr)*SEQ + k0 + sc0;
            *(uint4*)&Kt[sr][sc0]      = *(const uint4*)kp;
            *(uint4*)&Kt[sr][sc0 + 32] = *(const uint4*)(kp + 32);
            *(uint4*)&Vt[sr][sc0]      = *(const uint4*)vp;
            *(uint4*)&Vt[sr][sc0 + 32] = *(const uint4*)(vp + 32);
        }
        __syncthreads();

        // S = Q @ K^T : 4 key-subtiles of 16
        floatx4 sf[4];
#pragma unroll
        for (int t4 = 0; t4 < 4; ++t4) {
            floatx4 acc; acc[0]=0.f; acc[1]=0.f; acc[2]=0.f; acc[3]=0.f;
            const short8 kf0 = *(const short8*)&Kt[t4*16 + m16][quad*8];
            const short8 kf1 = *(const short8*)&Kt[t4*16 + m16][32 + quad*8];
            acc = __builtin_amdgcn_mfma_f32_16x16x32_bf16(qf[0], kf0, acc, 0, 0, 0);
            acc = __builtin_amdgcn_mfma_f32_16x16x32_bf16(qf[1], kf1, acc, 0, 0, 0);
            sf[t4] = acc;
        }

        // scale + causal mask (only diagonal tile needs it) + row max
        const bool need_mask = (kt == qt);
        float mx[4];
#pragma unroll
        for (int r = 0; r < 4; ++r) {
            const int qg = qw0 + quad*4 + r;
            float vmax = NEG_BIG;
#pragma unroll
            for (int t4 = 0; t4 < 4; ++t4) {
                float s = sf[t4][r] * 0.125f;
                if (need_mask && (k0 + t4*16 + m16 > qg)) s = NEG_BIG;
                sf[t4][r] = s;
                vmax = fmaxf(vmax, s);
            }
            mx[r] = vmax;
        }
#pragma unroll
        for (int off = 1; off < 16; off <<= 1)
#pragma unroll
            for (int r = 0; r < 4; ++r) mx[r] = fmaxf(mx[r], __shfl_xor(mx[r], off));

        float alpha[4], rs[4];
#pragma unroll
        for (int r = 0; r < 4; ++r) {
            const float mnew = fmaxf(mrow[r], mx[r]);
            alpha[r] = __expf(mrow[r] - mnew);
            mrow[r] = mnew;
            float sum = 0.f;
#pragma unroll
            for (int t4 = 0; t4 < 4; ++t4) {
                const float p = __expf(sf[t4][r] - mnew);
                sf[t4][r] = p;
                sum += p;
            }
            rs[r] = sum;
        }
#pragma unroll
        for (int off = 1; off < 16; off <<= 1)
#pragma unroll
            for (int r = 0; r < 4; ++r) rs[r] += __shfl_xor(rs[r], off);
#pragma unroll
        for (int r = 0; r < 4; ++r) lrow[r] = lrow[r]*alpha[r] + rs[r];
#pragma unroll
        for (int nt = 0; nt < 4; ++nt)
#pragma unroll
            for (int r = 0; r < 4; ++r) of[nt][r] *= alpha[r];

        // P -> LDS (C-layout scatter), then wave-local A-frag reads
#pragma unroll
        for (int t4 = 0; t4 < 4; ++t4)
#pragma unroll
            for (int r = 0; r < 4; ++r)
                Ps[w][quad*4 + r][t4*16 + m16] = f2bf_rne(sf[t4][r]);

        const short8 pf0 = *(const short8*)&Ps[w][m16][quad*8];
        const short8 pf1 = *(const short8*)&Ps[w][m16][32 + quad*8];
#pragma unroll
        for (int nt = 0; nt < 4; ++nt) {
            const short8 vf0 = *(const short8*)&Vt[nt*16 + m16][quad*8];
            const short8 vf1 = *(const short8*)&Vt[nt*16 + m16][32 + quad*8];
            of[nt] = __builtin_amdgcn_mfma_f32_16x16x32_bf16(pf0, vf0, of[nt], 0, 0, 0);
            of[nt] = __builtin_amdgcn_mfma_f32_16x16x32_bf16(pf1, vf1, of[nt], 0, 0, 0);
        }
    }

    // normalize rows and store O (bf16)
    float rl[4];
#pragma unroll
    for (int r = 0; r < 4; ++r) rl[r] = 1.f / fmaxf(lrow[r], 1e-20f);
#pragma unroll
    for (int nt = 0; nt < 4; ++nt) {
#pragma unroll
        for (int r = 0; r < 4; ++r) {
            const size_t idx = (size_t)(b*SEQ + qw0 + quad*4 + r)*DMODEL
                             + h*DHEAD + nt*16 + m16;
            Og[idx] = __float2bfloat16(of[nt][r] * rl[r]);
        }
    }
}

// Diagnostic: encode ws_size (MB) into the output if ws is too small.
__global__ void diag_fill(float* out, int n, float val) {
    int i = blockIdx.x*blockDim.x + threadIdx.x;
    if (i < n) out[i] = val;
}

// ---------------------------------------------------------------------------
extern "C" void kernel_launch(void* const* d_in, const int* in_sizes, int n_in,
                              void* d_out, int out_size, void* d_ws, size_t ws_size,
                              hipStream_t stream) {
    const float* x     = (const float*)d_in[0];
    const float* W_qkv = (const float*)d_in[1];
    const float* b_qkv = (const float*)d_in[2];
    const float* W_out = (const float*)d_in[3];
    const float* b_out = (const float*)d_in[4];

    if (ws_size < WS_NEED) {
        const float val = 100.f + (float)(ws_size >> 20);
        diag_fill<<<(out_size + 255)/256, 256, 0, stream>>>((float*)d_out, out_size, val);
        return;
    }

    // Buffer plan (bf16 element offsets):
    //   d_out lo: Q [8192,1024]      d_out hi: VT then (dead) -> final fp32 C
    //   ws lo   : K [8192,1024]      ws hi   : V, then O after attention
    bf16* Qb  = (bf16*)d_out;
    bf16* VTb = (bf16*)d_out + (size_t)MROWS*DMODEL;
    bf16* Kb  = (bf16*)d_ws;
    bf16* Vb  = (bf16*)d_ws + (size_t)MROWS*DMODEL;   // V, later O

    // 1) QKV projections (fp32 A/B -> bf16 C)
    {
        dim3 g(DMODEL/BN, MROWS/BM);
        gemm_bias<false,true><<<g, 256, 0, stream>>>(x, W_qkv,            b_qkv,            Qb,
                                                     DMODEL, DMODEL, DMODEL, QKV_N, DMODEL);
        gemm_bias<false,true><<<g, 256, 0, stream>>>(x, W_qkv + DMODEL,   b_qkv + DMODEL,   Kb,
                                                     DMODEL, DMODEL, DMODEL, QKV_N, DMODEL);
        gemm_bias<false,true><<<g, 256, 0, stream>>>(x, W_qkv + 2*DMODEL, b_qkv + 2*DMODEL, Vb,
                                                     DMODEL, DMODEL, DMODEL, QKV_N, DMODEL);
    }
    // 2) V -> VT (per (b,h): [2048 t][64 d] -> [64 d][2048 t])
    {
        dim3 g(SEQ/64, NHEADS, BATCH);
        transpose_v<<<g, 256, 0, stream>>>(Vb, VTb);
    }
    // 3) MFMA flash attention: O -> ws hi (V dead after transpose)
    {
        dim3 g(SEQ/64, NHEADS, BATCH);
        attn_mfma<<<g, 256, 0, stream>>>(Qb, Kb, VTb, Vb);
    }
    // 4) output projection: A = O bf16 (ws hi), C fp32 -> d_out (Q/VT dead)
    {
        dim3 g(DMODEL/BN, MROWS/BM);
        gemm_bias<true,false><<<g, 256, 0, stream>>>(Vb, W_out, b_out, (float*)d_out,
                                                     DMODEL, DMODEL, DMODEL, DMODEL, DMODEL);
    }
}

// Round 7
// 571.609 us; speedup vs baseline: 7.7394x; 1.9327x over previous
//
#include <hip/hip_runtime.h>
#include <hip/hip_bf16.h>

#define BATCH   4
#define SEQ     2048
#define DMODEL  1024
#define NHEADS  16
#define DHEAD   64
#define MROWS   (BATCH*SEQ)        // 8192
#define QKV_N   (3*DMODEL)         // 3072
#define NEG_BIG (-1.0e30f)
#define WS_NEED ((size_t)MROWS * 2*DMODEL * sizeof(__hip_bfloat16))  // 33,554,432

using bf16 = __hip_bfloat16;
typedef __attribute__((ext_vector_type(8))) short short8;   // 8 bf16 = 4 VGPR
typedef __attribute__((ext_vector_type(4))) float floatx4;

// Transposed bf16 weights, cast once per launch (module-scope: no hipMalloc).
__device__ __align__(16) unsigned short g_wqT[QKV_N * DMODEL];   // [3072][1024]
__device__ __align__(16) unsigned short g_woT[DMODEL * DMODEL];  // [1024][1024]

__device__ __forceinline__ float bf2f_bits(unsigned short u) {
    return __uint_as_float(((unsigned)u) << 16);
}
__device__ __forceinline__ unsigned short f2bf_rne(float f) {
    union { bf16 b; unsigned short u; } t;
    t.b = __float2bfloat16(f);
    return t.u;
}

// ---------------------------------------------------------------------------
// Weight transpose + cast: W fp32 [K=1024][N] -> dst bf16 [N][1024].
// 64x64 tiles via LDS.
// ---------------------------------------------------------------------------
__global__ __launch_bounds__(256) void transcast_w(
    const float* __restrict__ W, int N, int which)   // 0 -> g_wqT, 1 -> g_woT
{
    unsigned short* dst = which ? g_woT : g_wqT;
    __shared__ unsigned short T[64][72];
    const int n0 = blockIdx.x * 64, k0 = blockIdx.y * 64;
    const int tid = threadIdx.x;
    const int r = tid >> 2, c0 = (tid & 3) * 16;

#pragma unroll
    for (int it = 0; it < 4; ++it) {
        const float4 v = *(const float4*)(W + (size_t)(k0 + r)*N + n0 + c0 + it*4);
        T[r][c0 + it*4 + 0] = f2bf_rne(v.x);
        T[r][c0 + it*4 + 1] = f2bf_rne(v.y);
        T[r][c0 + it*4 + 2] = f2bf_rne(v.z);
        T[r][c0 + it*4 + 3] = f2bf_rne(v.w);
    }
    __syncthreads();
    const int nr = tid >> 2, kc0 = (tid & 3) * 16;
#pragma unroll
    for (int it = 0; it < 2; ++it) {
        union { uint4 u4; unsigned short us[8]; } o;
#pragma unroll
        for (int j = 0; j < 8; j++) o.us[j] = T[kc0 + it*8 + j][nr];
        *(uint4*)(dst + (size_t)(n0 + nr)*DMODEL + k0 + kc0 + it*8) = o.u4;
    }
}

// ---------------------------------------------------------------------------
// MFMA GEMM: C[M,N] = A[M,1024] @ B[1024,N] + bias, B given transposed in
// g_wqT/g_woT ([N][K] bf16). A fp32 (cast while staging) or bf16.
// 128x128 block tile, BK=32, 4 waves each computing 64x64 via 4x4 grid of
// 16x16x32 MFMA. Split output routing for the fused QKV gemm.
// C/D layout: col=lane&15, row=quad*4+reg. A/B frag: [m|n=lane&15][k=quad*8+j].
// ---------------------------------------------------------------------------
template<bool A_FP32, bool OUT_BF16, int WHICH_B>
__global__ __launch_bounds__(256) void gemm_mfma(
    const void* __restrict__ Av, const float* __restrict__ bias,
    void* __restrict__ C0, void* __restrict__ C1, void* __restrict__ C2)
{
    const unsigned short* BT = WHICH_B ? g_woT : g_wqT;
    __shared__ alignas(16) unsigned short As[128][40];  // [m][k] +8 pad
    __shared__ alignas(16) unsigned short Bs[128][40];  // [n][k] +8 pad

    const int tid = threadIdx.x;
    const int bm = blockIdx.y, bn = blockIdx.x;
    const int w = tid >> 6, lane = tid & 63;
    const int m16 = lane & 15, quad = lane >> 4;
    const int m0 = (w & 1) * 64, n0w = (w >> 1) * 64;

    const int sr = tid >> 2;          // staging row 0..63 (+64 on 2nd it)
    const int sc = (tid & 3) * 8;     // staging col {0,8,16,24}

    floatx4 acc[4][4];
#pragma unroll
    for (int i = 0; i < 4; i++)
#pragma unroll
        for (int j = 0; j < 4; j++) { acc[i][j][0]=0.f; acc[i][j][1]=0.f; acc[i][j][2]=0.f; acc[i][j][3]=0.f; }

    for (int k0 = 0; k0 < DMODEL; k0 += 32) {
        // ---- stage A (128x32) and B^T (128x32)
        uint4 aV[2], bV[2];
        float4 aF[2][2];
#pragma unroll
        for (int it = 0; it < 2; ++it) {
            const int r = sr + it*64;
            if (A_FP32) {
                const float* ap = (const float*)Av + (size_t)(bm*128 + r)*DMODEL + k0 + sc;
                aF[it][0] = *(const float4*)ap;
                aF[it][1] = *(const float4*)(ap + 4);
            } else {
                aV[it] = *(const uint4*)((const unsigned short*)Av + (size_t)(bm*128 + r)*DMODEL + k0 + sc);
            }
            bV[it] = *(const uint4*)(BT + (size_t)(bn*128 + r)*DMODEL + k0 + sc);
        }
        __syncthreads();
#pragma unroll
        for (int it = 0; it < 2; ++it) {
            const int r = sr + it*64;
            if (A_FP32) {
                union { uint4 u4; unsigned short us[8]; } t;
                t.us[0]=f2bf_rne(aF[it][0].x); t.us[1]=f2bf_rne(aF[it][0].y);
                t.us[2]=f2bf_rne(aF[it][0].z); t.us[3]=f2bf_rne(aF[it][0].w);
                t.us[4]=f2bf_rne(aF[it][1].x); t.us[5]=f2bf_rne(aF[it][1].y);
                t.us[6]=f2bf_rne(aF[it][1].z); t.us[7]=f2bf_rne(aF[it][1].w);
                *(uint4*)&As[r][sc] = t.u4;
            } else {
                *(uint4*)&As[r][sc] = aV[it];
            }
            *(uint4*)&Bs[r][sc] = bV[it];
        }
        __syncthreads();

        // ---- compute: 8 ds_read_b128 + 16 MFMA per wave
        short8 af[4], bf[4];
#pragma unroll
        for (int i = 0; i < 4; ++i) af[i] = *(const short8*)&As[m0 + i*16 + m16][quad*8];
#pragma unroll
        for (int j = 0; j < 4; ++j) bf[j] = *(const short8*)&Bs[n0w + j*16 + m16][quad*8];
#pragma unroll
        for (int i = 0; i < 4; ++i)
#pragma unroll
            for (int j = 0; j < 4; ++j)
                acc[i][j] = __builtin_amdgcn_mfma_f32_16x16x32_bf16(af[i], bf[j], acc[i][j], 0, 0, 0);
    }

    // ---- epilogue: bias + store (scalar; amortized over K=1024)
    const int gcolb = bn*128;                 // global col of block
    const int seg   = gcolb >> 10;            // 0..2 for QKV split, 0 else
    void* Cout = (seg == 0) ? C0 : (seg == 1) ? C1 : C2;

    float bv[4];
#pragma unroll
    for (int j = 0; j < 4; ++j) bv[j] = bias[gcolb + n0w + j*16 + m16];

#pragma unroll
    for (int i = 0; i < 4; ++i) {
#pragma unroll
        for (int r = 0; r < 4; ++r) {
            const int gm = bm*128 + m0 + i*16 + quad*4 + r;
#pragma unroll
            for (int j = 0; j < 4; ++j) {
                const int cc = ((gcolb + n0w + j*16 + m16) & 1023);
                const float v = acc[i][j][r] + bv[j];
                if (OUT_BF16)
                    ((bf16*)Cout)[(size_t)gm*DMODEL + cc] = __float2bfloat16(v);
                else
                    ((float*)Cout)[(size_t)gm*DMODEL + cc] = v;
            }
        }
    }
}

// ---------------------------------------------------------------------------
// V transpose: V[b*T+t][h*64+d] -> VT[((b*16+h)*64+d)*2048 + t]
// ---------------------------------------------------------------------------
__global__ __launch_bounds__(256) void transpose_v(
    const bf16* __restrict__ V, bf16* __restrict__ VT)
{
    __shared__ unsigned short T[64][65];
    const int b = blockIdx.z, hh = blockIdx.y;
    const int t0 = blockIdx.x * 64;
    const int tid = threadIdx.x;
    const int r = tid >> 2, c0 = (tid & 3) * 16;

#pragma unroll
    for (int it = 0; it < 2; ++it) {
        const int c = c0 + it*8;
        union { uint4 u4; unsigned short us[8]; } v;
        v.u4 = *(const uint4*)(V + (size_t)(b*SEQ + t0 + r)*DMODEL + hh*DHEAD + c);
#pragma unroll
        for (int j = 0; j < 8; j++) T[r][c+j] = v.us[j];
    }
    __syncthreads();
    const int d = tid >> 2, tc0 = (tid & 3) * 16;
#pragma unroll
    for (int it = 0; it < 2; ++it) {
        const int tc = tc0 + it*8;
        union { uint4 u4; unsigned short us[8]; } u;
#pragma unroll
        for (int j = 0; j < 8; j++) u.us[j] = T[tc+j][d];
        *(uint4*)(VT + (size_t)((b*NHEADS + hh)*DHEAD + d)*SEQ + t0 + tc) = u.u4;
    }
}

// ---------------------------------------------------------------------------
// MFMA flash attention (unchanged from round 6 — passed, 243 us)
// ---------------------------------------------------------------------------
__global__ __launch_bounds__(256) void attn_mfma(
    const bf16* __restrict__ Qg, const bf16* __restrict__ Kg,
    const bf16* __restrict__ VTg, bf16* __restrict__ Og)
{
    __shared__ alignas(16) unsigned short Kt[64][72];
    __shared__ alignas(16) unsigned short Vt[64][72];
    __shared__ alignas(16) unsigned short Ps[4][16][72];

    const int b = blockIdx.z, h = blockIdx.y, qt = blockIdx.x;
    const int q0 = qt * 64;
    const int tid = threadIdx.x;
    const int w = tid >> 6, lane = tid & 63;
    const int m16 = lane & 15, quad = lane >> 4;
    const int qw0 = q0 + w*16;

    short8 qf[2];
    {
        const size_t base = (size_t)(b*SEQ + qw0 + m16)*DMODEL + h*DHEAD + quad*8;
        qf[0] = *(const short8*)(Qg + base);
        qf[1] = *(const short8*)(Qg + base + 32);
    }

    floatx4 of[4];
    float mrow[4], lrow[4];
#pragma unroll
    for (int nt = 0; nt < 4; nt++) { of[nt][0]=0.f; of[nt][1]=0.f; of[nt][2]=0.f; of[nt][3]=0.f; }
#pragma unroll
    for (int r = 0; r < 4; r++) { mrow[r] = NEG_BIG; lrow[r] = 0.f; }

    const int sr  = tid >> 2;
    const int sc0 = (tid & 3) * 8;

    const int nkt = qt + 1;
    for (int kt = 0; kt < nkt; ++kt) {
        const int k0 = kt * 64;
        __syncthreads();
        {
            const bf16* kp = Kg  + (size_t)(b*SEQ + k0 + sr)*DMODEL + h*DHEAD + sc0;
            const bf16* vp = VTg + (size_t)((b*NHEADS + h)*DHEAD + sr)*SEQ + k0 + sc0;
            *(uint4*)&Kt[sr][sc0]      = *(const uint4*)kp;
            *(uint4*)&Kt[sr][sc0 + 32] = *(const uint4*)(kp + 32);
            *(uint4*)&Vt[sr][sc0]      = *(const uint4*)vp;
            *(uint4*)&Vt[sr][sc0 + 32] = *(const uint4*)(vp + 32);
        }
        __syncthreads();

        floatx4 sf[4];
#pragma unroll
        for (int t4 = 0; t4 < 4; ++t4) {
            floatx4 a; a[0]=0.f; a[1]=0.f; a[2]=0.f; a[3]=0.f;
            const short8 kf0 = *(const short8*)&Kt[t4*16 + m16][quad*8];
            const short8 kf1 = *(const short8*)&Kt[t4*16 + m16][32 + quad*8];
            a = __builtin_amdgcn_mfma_f32_16x16x32_bf16(qf[0], kf0, a, 0, 0, 0);
            a = __builtin_amdgcn_mfma_f32_16x16x32_bf16(qf[1], kf1, a, 0, 0, 0);
            sf[t4] = a;
        }

        const bool need_mask = (kt == qt);
        float mx[4];
#pragma unroll
        for (int r = 0; r < 4; ++r) {
            const int qg = qw0 + quad*4 + r;
            float vmax = NEG_BIG;
#pragma unroll
            for (int t4 = 0; t4 < 4; ++t4) {
                float s = sf[t4][r] * 0.125f;
                if (need_mask && (k0 + t4*16 + m16 > qg)) s = NEG_BIG;
                sf[t4][r] = s;
                vmax = fmaxf(vmax, s);
            }
            mx[r] = vmax;
        }
#pragma unroll
        for (int off = 1; off < 16; off <<= 1)
#pragma unroll
            for (int r = 0; r < 4; ++r) mx[r] = fmaxf(mx[r], __shfl_xor(mx[r], off));

        float alpha[4], rs[4];
#pragma unroll
        for (int r = 0; r < 4; ++r) {
            const float mnew = fmaxf(mrow[r], mx[r]);
            alpha[r] = __expf(mrow[r] - mnew);
            mrow[r] = mnew;
            float sum = 0.f;
#pragma unroll
            for (int t4 = 0; t4 < 4; ++t4) {
                const float p = __expf(sf[t4][r] - mnew);
                sf[t4][r] = p;
                sum += p;
            }
            rs[r] = sum;
        }
#pragma unroll
        for (int off = 1; off < 16; off <<= 1)
#pragma unroll
            for (int r = 0; r < 4; ++r) rs[r] += __shfl_xor(rs[r], off);
#pragma unroll
        for (int r = 0; r < 4; ++r) lrow[r] = lrow[r]*alpha[r] + rs[r];
#pragma unroll
        for (int nt = 0; nt < 4; ++nt)
#pragma unroll
            for (int r = 0; r < 4; ++r) of[nt][r] *= alpha[r];

#pragma unroll
        for (int t4 = 0; t4 < 4; ++t4)
#pragma unroll
            for (int r = 0; r < 4; ++r)
                Ps[w][quad*4 + r][t4*16 + m16] = f2bf_rne(sf[t4][r]);

        const short8 pf0 = *(const short8*)&Ps[w][m16][quad*8];
        const short8 pf1 = *(const short8*)&Ps[w][m16][32 + quad*8];
#pragma unroll
        for (int nt = 0; nt < 4; ++nt) {
            const short8 vf0 = *(const short8*)&Vt[nt*16 + m16][quad*8];
            const short8 vf1 = *(const short8*)&Vt[nt*16 + m16][32 + quad*8];
            of[nt] = __builtin_amdgcn_mfma_f32_16x16x32_bf16(pf0, vf0, of[nt], 0, 0, 0);
            of[nt] = __builtin_amdgcn_mfma_f32_16x16x32_bf16(pf1, vf1, of[nt], 0, 0, 0);
        }
    }

    float rl[4];
#pragma unroll
    for (int r = 0; r < 4; ++r) rl[r] = 1.f / fmaxf(lrow[r], 1e-20f);
#pragma unroll
    for (int nt = 0; nt < 4; ++nt) {
#pragma unroll
        for (int r = 0; r < 4; ++r) {
            const size_t idx = (size_t)(b*SEQ + qw0 + quad*4 + r)*DMODEL
                             + h*DHEAD + nt*16 + m16;
            Og[idx] = __float2bfloat16(of[nt][r] * rl[r]);
        }
    }
}

__global__ void diag_fill(float* out, int n, float val) {
    int i = blockIdx.x*blockDim.x + threadIdx.x;
    if (i < n) out[i] = val;
}

// ---------------------------------------------------------------------------
extern "C" void kernel_launch(void* const* d_in, const int* in_sizes, int n_in,
                              void* d_out, int out_size, void* d_ws, size_t ws_size,
                              hipStream_t stream) {
    const float* x     = (const float*)d_in[0];
    const float* W_qkv = (const float*)d_in[1];
    const float* b_qkv = (const float*)d_in[2];
    const float* W_out = (const float*)d_in[3];
    const float* b_out = (const float*)d_in[4];

    if (ws_size < WS_NEED) {
        const float val = 100.f + (float)(ws_size >> 20);
        diag_fill<<<(out_size + 255)/256, 256, 0, stream>>>((float*)d_out, out_size, val);
        return;
    }

    // Buffers: d_out lo = Q bf16, d_out hi = VT bf16 (both dead before final
    // fp32 C overwrites d_out). ws lo = K bf16, ws hi = V bf16 -> O bf16.
    bf16* Qb  = (bf16*)d_out;
    bf16* VTb = (bf16*)d_out + (size_t)MROWS*DMODEL;
    bf16* Kb  = (bf16*)d_ws;
    bf16* Vb  = (bf16*)d_ws + (size_t)MROWS*DMODEL;

    // 0) weight transpose + cast into static device buffers
    {
        dim3 gq(QKV_N/64, DMODEL/64);
        transcast_w<<<gq, 256, 0, stream>>>(W_qkv, QKV_N, 0);
        dim3 go(DMODEL/64, DMODEL/64);
        transcast_w<<<go, 256, 0, stream>>>(W_out, DMODEL, 1);
    }
    // 1) fused QKV projection (MFMA): x fp32 -> Q,K,V bf16
    {
        dim3 g(QKV_N/128, MROWS/128);
        gemm_mfma<true, true, 0><<<g, 256, 0, stream>>>(x, b_qkv, Qb, Kb, Vb);
    }
    // 2) V -> VT
    {
        dim3 g(SEQ/64, NHEADS, BATCH);
        transpose_v<<<g, 256, 0, stream>>>(Vb, VTb);
    }
    // 3) MFMA flash attention: O -> ws hi (V dead)
    {
        dim3 g(SEQ/64, NHEADS, BATCH);
        attn_mfma<<<g, 256, 0, stream>>>(Qb, Kb, VTb, Vb);
    }
    // 4) output projection (MFMA): O bf16 -> fp32 d_out
    {
        dim3 g(DMODEL/128, MROWS/128);
        gemm_mfma<false, false, 1><<<g, 256, 0, stream>>>(Vb, b_out, d_out, d_out, d_out);
    }
}

// Round 8
// 346.238 us; speedup vs baseline: 12.7771x; 1.6509x over previous
//
#include <hip/hip_runtime.h>
#include <hip/hip_bf16.h>

#define BATCH   4
#define SEQ     2048
#define DMODEL  1024
#define NHEADS  16
#define DHEAD   64
#define MROWS   (BATCH*SEQ)        // 8192
#define QKV_N   (3*DMODEL)         // 3072
#define NEG_BIG (-1.0e30f)
#define WS_NEED ((size_t)MROWS * 2*DMODEL * sizeof(__hip_bfloat16))  // 33,554,432

using bf16 = __hip_bfloat16;
typedef __attribute__((ext_vector_type(8))) short short8;
typedef __attribute__((ext_vector_type(4))) float floatx4;

// Static device buffers (module BSS; no hipMalloc needed)
__device__ __align__(16) unsigned short g_wqT[QKV_N * DMODEL];   // W_qkv^T bf16
__device__ __align__(16) unsigned short g_woT[DMODEL * DMODEL];  // W_out^T bf16
__device__ __align__(16) unsigned short g_xb [MROWS * DMODEL];   // x bf16

__device__ __forceinline__ unsigned short f2bf_rne(float f) {
    union { bf16 b; unsigned short u; } t;
    t.b = __float2bfloat16(f);
    return t.u;
}

// ---------------------------------------------------------------------------
// x fp32 -> bf16 (8 elems/thread)
// ---------------------------------------------------------------------------
__global__ __launch_bounds__(256) void cast_x(const float* __restrict__ x) {
    const size_t i = ((size_t)blockIdx.x*256 + threadIdx.x)*8;
    const float4 a = *(const float4*)(x + i);
    const float4 b = *(const float4*)(x + i + 4);
    union { uint4 u4; unsigned short us[8]; } o;
    o.us[0]=f2bf_rne(a.x); o.us[1]=f2bf_rne(a.y); o.us[2]=f2bf_rne(a.z); o.us[3]=f2bf_rne(a.w);
    o.us[4]=f2bf_rne(b.x); o.us[5]=f2bf_rne(b.y); o.us[6]=f2bf_rne(b.z); o.us[7]=f2bf_rne(b.w);
    *(uint4*)(g_xb + i) = o.u4;
}

// ---------------------------------------------------------------------------
// Weight transpose + cast: W fp32 [1024][N] -> dst bf16 [N][1024]
// ---------------------------------------------------------------------------
__global__ __launch_bounds__(256) void transcast_w(
    const float* __restrict__ W, int N, int which)
{
    unsigned short* dst = which ? g_woT : g_wqT;
    __shared__ unsigned short T[64][72];
    const int n0 = blockIdx.x * 64, k0 = blockIdx.y * 64;
    const int tid = threadIdx.x;
    const int r = tid >> 2, c0 = (tid & 3) * 16;

#pragma unroll
    for (int it = 0; it < 4; ++it) {
        const float4 v = *(const float4*)(W + (size_t)(k0 + r)*N + n0 + c0 + it*4);
        T[r][c0 + it*4 + 0] = f2bf_rne(v.x);
        T[r][c0 + it*4 + 1] = f2bf_rne(v.y);
        T[r][c0 + it*4 + 2] = f2bf_rne(v.z);
        T[r][c0 + it*4 + 3] = f2bf_rne(v.w);
    }
    __syncthreads();
    const int nr = tid >> 2, kc0 = (tid & 3) * 16;
#pragma unroll
    for (int it = 0; it < 2; ++it) {
        union { uint4 u4; unsigned short us[8]; } o;
#pragma unroll
        for (int j = 0; j < 8; j++) o.us[j] = T[kc0 + it*8 + j][nr];
        *(uint4*)(dst + (size_t)(n0 + nr)*DMODEL + k0 + kc0 + it*8) = o.u4;
    }
}

// ---------------------------------------------------------------------------
// MFMA GEMM, all-bf16 inputs, software-pipelined staging.
// A: g_xb (WHICH_A=0) or runtime bf16 ptr (WHICH_A=1). B: g_wqT / g_woT.
// ---------------------------------------------------------------------------
template<int WHICH_A, bool OUT_BF16, int WHICH_B>
__global__ __launch_bounds__(256) void gemm_mfma(
    const void* __restrict__ Av, const float* __restrict__ bias,
    void* __restrict__ C0, void* __restrict__ C1, void* __restrict__ C2)
{
    const unsigned short* A  = WHICH_A ? (const unsigned short*)Av : g_xb;
    const unsigned short* BT = WHICH_B ? g_woT : g_wqT;
    __shared__ alignas(16) unsigned short As[128][40];
    __shared__ alignas(16) unsigned short Bs[128][40];

    const int tid = threadIdx.x;
    const int bm = blockIdx.y, bn = blockIdx.x;
    const int w = tid >> 6, lane = tid & 63;
    const int m16 = lane & 15, quad = lane >> 4;
    const int m0 = (w & 1) * 64, n0w = (w >> 1) * 64;

    const int sr = tid >> 2;
    const int sc = (tid & 3) * 8;

    floatx4 acc[4][4];
#pragma unroll
    for (int i = 0; i < 4; i++)
#pragma unroll
        for (int j = 0; j < 4; j++) { acc[i][j][0]=0.f; acc[i][j][1]=0.f; acc[i][j][2]=0.f; acc[i][j][3]=0.f; }

    const unsigned short* aG0 = A  + (size_t)(bm*128 + sr)*DMODEL + sc;
    const unsigned short* aG1 = A  + (size_t)(bm*128 + sr + 64)*DMODEL + sc;
    const unsigned short* bG0 = BT + (size_t)(bn*128 + sr)*DMODEL + sc;
    const unsigned short* bG1 = BT + (size_t)(bn*128 + sr + 64)*DMODEL + sc;

    uint4 aV0 = *(const uint4*)aG0;
    uint4 aV1 = *(const uint4*)aG1;
    uint4 bV0 = *(const uint4*)bG0;
    uint4 bV1 = *(const uint4*)bG1;

    for (int k0 = 0; k0 < DMODEL; k0 += 32) {
        __syncthreads();
        *(uint4*)&As[sr][sc]      = aV0;
        *(uint4*)&As[sr + 64][sc] = aV1;
        *(uint4*)&Bs[sr][sc]      = bV0;
        *(uint4*)&Bs[sr + 64][sc] = bV1;
        __syncthreads();
        if (k0 + 32 < DMODEL) {     // prefetch next K-slab during compute
            aV0 = *(const uint4*)(aG0 + k0 + 32);
            aV1 = *(const uint4*)(aG1 + k0 + 32);
            bV0 = *(const uint4*)(bG0 + k0 + 32);
            bV1 = *(const uint4*)(bG1 + k0 + 32);
        }
        short8 af[4], bf4[4];
#pragma unroll
        for (int i = 0; i < 4; ++i) af[i]  = *(const short8*)&As[m0 + i*16 + m16][quad*8];
#pragma unroll
        for (int j = 0; j < 4; ++j) bf4[j] = *(const short8*)&Bs[n0w + j*16 + m16][quad*8];
#pragma unroll
        for (int i = 0; i < 4; ++i)
#pragma unroll
            for (int j = 0; j < 4; ++j)
                acc[i][j] = __builtin_amdgcn_mfma_f32_16x16x32_bf16(af[i], bf4[j], acc[i][j], 0, 0, 0);
    }

    const int gcolb = bn*128;
    const int seg   = gcolb >> 10;
    void* Cout = (seg == 0) ? C0 : (seg == 1) ? C1 : C2;

    float bv[4];
#pragma unroll
    for (int j = 0; j < 4; ++j) bv[j] = bias[gcolb + n0w + j*16 + m16];

#pragma unroll
    for (int i = 0; i < 4; ++i) {
#pragma unroll
        for (int r = 0; r < 4; ++r) {
            const int gm = bm*128 + m0 + i*16 + quad*4 + r;
#pragma unroll
            for (int j = 0; j < 4; ++j) {
                const int cc = ((gcolb + n0w + j*16 + m16) & 1023);
                const float v = acc[i][j][r] + bv[j];
                if (OUT_BF16)
                    ((bf16*)Cout)[(size_t)gm*DMODEL + cc] = __float2bfloat16(v);
                else
                    ((float*)Cout)[(size_t)gm*DMODEL + cc] = v;
            }
        }
    }
}

// ---------------------------------------------------------------------------
// V transpose: V[b*T+t][h*64+d] -> VT[((b*16+h)*64+d)*2048 + t]
// ---------------------------------------------------------------------------
__global__ __launch_bounds__(256) void transpose_v(
    const bf16* __restrict__ V, bf16* __restrict__ VT)
{
    __shared__ unsigned short T[64][65];
    const int b = blockIdx.z, hh = blockIdx.y;
    const int t0 = blockIdx.x * 64;
    const int tid = threadIdx.x;
    const int r = tid >> 2, c0 = (tid & 3) * 16;

#pragma unroll
    for (int it = 0; it < 2; ++it) {
        const int c = c0 + it*8;
        union { uint4 u4; unsigned short us[8]; } v;
        v.u4 = *(const uint4*)(V + (size_t)(b*SEQ + t0 + r)*DMODEL + hh*DHEAD + c);
#pragma unroll
        for (int j = 0; j < 8; j++) T[r][c+j] = v.us[j];
    }
    __syncthreads();
    const int d = tid >> 2, tc0 = (tid & 3) * 16;
#pragma unroll
    for (int it = 0; it < 2; ++it) {
        const int tc = tc0 + it*8;
        union { uint4 u4; unsigned short us[8]; } u;
#pragma unroll
        for (int j = 0; j < 8; j++) u.us[j] = T[tc+j][d];
        *(uint4*)(VT + (size_t)((b*NHEADS + hh)*DHEAD + d)*SEQ + t0 + tc) = u.u4;
    }
}

// ---------------------------------------------------------------------------
// MFMA flash attention v2. 128-query tiles; block = paired q-tiles {p, 15-p}
// (uniform 34 key-tile iters). 4 waves x 32 q-rows. Double-buffered 64-key
// K/V LDS tiles, ONE barrier per iter. Online softmax per (i,r) row group.
// Layouts (HW-verified): C/D col=lane&15(key/d), row=quad*4+reg(q);
// A/B frag [m|n=lane&15][k=quad*8+j].
// ---------------------------------------------------------------------------
__global__ __launch_bounds__(256, 2) void attn_mfma2(
    const bf16* __restrict__ Qg, const bf16* __restrict__ Kg,
    const bf16* __restrict__ VTg, bf16* __restrict__ Og)
{
    __shared__ alignas(16) unsigned short Kt[2][64][72];   // [buf][key][d]
    __shared__ alignas(16) unsigned short Vt[2][64][72];   // [buf][d][key]
    __shared__ alignas(16) unsigned short Ps[4][32][72];   // [wave][q][key]

    const int x = blockIdx.x;
    const int b = x >> 7, h = (x >> 3) & 15, p = x & 7;
    const int tid = threadIdx.x;
    const int w = tid >> 6, lane = tid & 63;
    const int m16 = lane & 15, quad = lane >> 4;
    const int sr = tid >> 2, sc0 = (tid & 3) * 8;
    const size_t bh = (size_t)(b*NHEADS + h);

    for (int seg = 0; seg < 2; ++seg) {
        const int qt  = seg ? (15 - p) : p;
        const int nkt = 2*qt + 2;
        const int qrow0 = qt*128 + w*32;

        short8 qf[2][2];
#pragma unroll
        for (int i = 0; i < 2; ++i)
#pragma unroll
            for (int c = 0; c < 2; ++c)
                qf[i][c] = *(const short8*)(Qg + (size_t)(b*SEQ + qrow0 + i*16 + m16)*DMODEL
                                            + h*DHEAD + c*32 + quad*8);

        floatx4 of[2][4];
        float mrow[2][4], lrow[2][4];
#pragma unroll
        for (int i = 0; i < 2; ++i) {
#pragma unroll
            for (int nt = 0; nt < 4; ++nt) { of[i][nt][0]=0.f; of[i][nt][1]=0.f; of[i][nt][2]=0.f; of[i][nt][3]=0.f; }
#pragma unroll
            for (int r = 0; r < 4; ++r) { mrow[i][r] = NEG_BIG; lrow[i][r] = 0.f; }
        }

        // ---- stage tile 0 into buf 0
        {
            const bf16* kp = Kg  + (size_t)(b*SEQ + sr)*DMODEL + h*DHEAD + sc0;
            const bf16* vp = VTg + (bh*DHEAD + sr)*SEQ + sc0;
            const uint4 a0 = *(const uint4*)kp, a1 = *(const uint4*)(kp + 32);
            const uint4 b0 = *(const uint4*)vp, b1 = *(const uint4*)(vp + 32);
            __syncthreads();   // protect buffers from previous segment's readers
            *(uint4*)&Kt[0][sr][sc0]      = a0;
            *(uint4*)&Kt[0][sr][sc0 + 32] = a1;
            *(uint4*)&Vt[0][sr][sc0]      = b0;
            *(uint4*)&Vt[0][sr][sc0 + 32] = b1;
            __syncthreads();
        }

        for (int kt = 0; kt < nkt; ++kt) {
            const int buf = kt & 1;
            const int k064 = kt * 64;
            const bool pre = (kt + 1 < nkt);
            uint4 kr0, kr1, vr0, vr1;
            if (pre) {   // issue next tile's global loads; land after compute
                const bf16* kp = Kg  + (size_t)(b*SEQ + k064 + 64 + sr)*DMODEL + h*DHEAD + sc0;
                const bf16* vp = VTg + (bh*DHEAD + sr)*SEQ + k064 + 64 + sc0;
                kr0 = *(const uint4*)kp; kr1 = *(const uint4*)(kp + 32);
                vr0 = *(const uint4*)vp; vr1 = *(const uint4*)(vp + 32);
            }

            // ---- S = Q K^T (16 MFMA)
            floatx4 sf[2][4];
#pragma unroll
            for (int t4 = 0; t4 < 4; ++t4) {
                const short8 kf0 = *(const short8*)&Kt[buf][t4*16 + m16][quad*8];
                const short8 kf1 = *(const short8*)&Kt[buf][t4*16 + m16][32 + quad*8];
#pragma unroll
                for (int i = 0; i < 2; ++i) {
                    floatx4 a; a[0]=0.f; a[1]=0.f; a[2]=0.f; a[3]=0.f;
                    a = __builtin_amdgcn_mfma_f32_16x16x32_bf16(qf[i][0], kf0, a, 0, 0, 0);
                    a = __builtin_amdgcn_mfma_f32_16x16x32_bf16(qf[i][1], kf1, a, 0, 0, 0);
                    sf[i][t4] = a;
                }
            }

            // ---- online softmax
            const bool need_mask = (kt >= 2*qt);
#pragma unroll
            for (int i = 0; i < 2; ++i) {
                float mx[4];
#pragma unroll
                for (int r = 0; r < 4; ++r) {
                    const int qg = qrow0 + i*16 + quad*4 + r;
                    float vm = NEG_BIG;
#pragma unroll
                    for (int t4 = 0; t4 < 4; ++t4) {
                        float s = sf[i][t4][r] * 0.125f;
                        if (need_mask && (k064 + t4*16 + m16 > qg)) s = NEG_BIG;
                        sf[i][t4][r] = s;
                        vm = fmaxf(vm, s);
                    }
                    mx[r] = vm;
                }
#pragma unroll
                for (int off = 1; off < 16; off <<= 1)
#pragma unroll
                    for (int r = 0; r < 4; ++r) mx[r] = fmaxf(mx[r], __shfl_xor(mx[r], off));

                float rs[4], alpha[4];
#pragma unroll
                for (int r = 0; r < 4; ++r) {
                    const float mnew = fmaxf(mrow[i][r], mx[r]);
                    alpha[r] = __expf(mrow[i][r] - mnew);
                    mrow[i][r] = mnew;
                    float sum = 0.f;
#pragma unroll
                    for (int t4 = 0; t4 < 4; ++t4) {
                        const float pv = __expf(sf[i][t4][r] - mnew);
                        sf[i][t4][r] = pv;
                        sum += pv;
                    }
                    rs[r] = sum;
                }
#pragma unroll
                for (int off = 1; off < 16; off <<= 1)
#pragma unroll
                    for (int r = 0; r < 4; ++r) rs[r] += __shfl_xor(rs[r], off);
#pragma unroll
                for (int r = 0; r < 4; ++r) lrow[i][r] = lrow[i][r]*alpha[r] + rs[r];
#pragma unroll
                for (int nt = 0; nt < 4; ++nt)
#pragma unroll
                    for (int r = 0; r < 4; ++r) of[i][nt][r] *= alpha[r];
#pragma unroll
                for (int t4 = 0; t4 < 4; ++t4)
#pragma unroll
                    for (int r = 0; r < 4; ++r)
                        Ps[w][i*16 + quad*4 + r][t4*16 + m16] = f2bf_rne(sf[i][t4][r]);
            }

            // ---- O += P V (16 MFMA); Ps is wave-local (no barrier needed)
            short8 pf[2][2];
#pragma unroll
            for (int i = 0; i < 2; ++i)
#pragma unroll
                for (int c = 0; c < 2; ++c)
                    pf[i][c] = *(const short8*)&Ps[w][i*16 + m16][c*32 + quad*8];
#pragma unroll
            for (int nt = 0; nt < 4; ++nt) {
                const short8 vf0 = *(const short8*)&Vt[buf][nt*16 + m16][quad*8];
                const short8 vf1 = *(const short8*)&Vt[buf][nt*16 + m16][32 + quad*8];
#pragma unroll
                for (int i = 0; i < 2; ++i) {
                    of[i][nt] = __builtin_amdgcn_mfma_f32_16x16x32_bf16(pf[i][0], vf0, of[i][nt], 0, 0, 0);
                    of[i][nt] = __builtin_amdgcn_mfma_f32_16x16x32_bf16(pf[i][1], vf1, of[i][nt], 0, 0, 0);
                }
            }

            if (pre) {   // publish next tile into the other buffer
                *(uint4*)&Kt[buf^1][sr][sc0]      = kr0;
                *(uint4*)&Kt[buf^1][sr][sc0 + 32] = kr1;
                *(uint4*)&Vt[buf^1][sr][sc0]      = vr0;
                *(uint4*)&Vt[buf^1][sr][sc0 + 32] = vr1;
            }
            __syncthreads();
        }

        // ---- normalize + store O
#pragma unroll
        for (int i = 0; i < 2; ++i) {
            float rl[4];
#pragma unroll
            for (int r = 0; r < 4; ++r) rl[r] = 1.f / fmaxf(lrow[i][r], 1e-20f);
#pragma unroll
            for (int nt = 0; nt < 4; ++nt)
#pragma unroll
                for (int r = 0; r < 4; ++r) {
                    const int row = qrow0 + i*16 + quad*4 + r;
                    Og[(size_t)(b*SEQ + row)*DMODEL + h*DHEAD + nt*16 + m16] =
                        __float2bfloat16(of[i][nt][r] * rl[r]);
                }
        }
    }
}

__global__ void diag_fill(float* out, int n, float val) {
    int i = blockIdx.x*blockDim.x + threadIdx.x;
    if (i < n) out[i] = val;
}

// ---------------------------------------------------------------------------
extern "C" void kernel_launch(void* const* d_in, const int* in_sizes, int n_in,
                              void* d_out, int out_size, void* d_ws, size_t ws_size,
                              hipStream_t stream) {
    const float* x     = (const float*)d_in[0];
    const float* W_qkv = (const float*)d_in[1];
    const float* b_qkv = (const float*)d_in[2];
    const float* W_out = (const float*)d_in[3];
    const float* b_out = (const float*)d_in[4];

    if (ws_size < WS_NEED) {
        const float val = 100.f + (float)(ws_size >> 20);
        diag_fill<<<(out_size + 255)/256, 256, 0, stream>>>((float*)d_out, out_size, val);
        return;
    }

    bf16* Qb  = (bf16*)d_out;                                // d_out lo
    bf16* VTb = (bf16*)d_out + (size_t)MROWS*DMODEL;         // d_out hi
    bf16* Kb  = (bf16*)d_ws;                                 // ws lo
    bf16* Vb  = (bf16*)d_ws + (size_t)MROWS*DMODEL;          // ws hi: V -> O

    // 0) casts: x -> bf16, weights -> transposed bf16
    cast_x<<<MROWS*DMODEL/2048, 256, 0, stream>>>(x);
    {
        dim3 gq(QKV_N/64, DMODEL/64);
        transcast_w<<<gq, 256, 0, stream>>>(W_qkv, QKV_N, 0);
        dim3 go(DMODEL/64, DMODEL/64);
        transcast_w<<<go, 256, 0, stream>>>(W_out, DMODEL, 1);
    }
    // 1) fused QKV projection (all-bf16 MFMA)
    {
        dim3 g(QKV_N/128, MROWS/128);
        gemm_mfma<0, true, 0><<<g, 256, 0, stream>>>(nullptr, b_qkv, Qb, Kb, Vb);
    }
    // 2) V -> VT
    {
        dim3 g(SEQ/64, NHEADS, BATCH);
        transpose_v<<<g, 256, 0, stream>>>(Vb, VTb);
    }
    // 3) flash attention v2: O -> ws hi (V dead)
    {
        attn_mfma2<<<512, 256, 0, stream>>>(Qb, Kb, VTb, Vb);
    }
    // 4) output projection: O bf16 -> fp32 d_out (Q/VT dead)
    {
        dim3 g(DMODEL/128, MROWS/128);
        gemm_mfma<1, false, 1><<<g, 256, 0, stream>>>(Vb, b_out, d_out, d_out, d_out);
    }
}

// Round 9
// 340.837 us; speedup vs baseline: 12.9796x; 1.0158x over previous
//
#include <hip/hip_runtime.h>
#include <hip/hip_bf16.h>

#define BATCH   4
#define SEQ     2048
#define DMODEL  1024
#define NHEADS  16
#define DHEAD   64
#define MROWS   (BATCH*SEQ)        // 8192
#define QKV_N   (3*DMODEL)         // 3072
#define NEG_BIG (-1.0e30f)
#define WS_NEED ((size_t)MROWS * 2*DMODEL * sizeof(__hip_bfloat16))  // 33,554,432

using bf16 = __hip_bfloat16;
typedef __attribute__((ext_vector_type(8))) short short8;
typedef __attribute__((ext_vector_type(4))) float floatx4;

// Static device buffers (module BSS; no hipMalloc)
__device__ __align__(16) unsigned short g_wqT[QKV_N * DMODEL];   // W_qkv^T bf16
__device__ __align__(16) unsigned short g_woT[DMODEL * DMODEL];  // W_out^T bf16
__device__ __align__(16) unsigned short g_xb [MROWS * DMODEL];   // x bf16

__device__ __forceinline__ unsigned short f2bf_rne(float f) {
    union { bf16 b; unsigned short u; } t;
    t.b = __float2bfloat16(f);
    return t.u;
}

// async global->LDS, 16B per lane; LDS dest = wave-uniform base + lane*16
__device__ __forceinline__ void gload_lds16(const void* g, void* l) {
    __builtin_amdgcn_global_load_lds(
        (const __attribute__((address_space(1))) unsigned*)g,
        (__attribute__((address_space(3))) unsigned*)l, 16, 0, 0);
}

// ---------------------------------------------------------------------------
// x fp32 -> bf16
// ---------------------------------------------------------------------------
__global__ __launch_bounds__(256) void cast_x(const float* __restrict__ x) {
    const size_t i = ((size_t)blockIdx.x*256 + threadIdx.x)*8;
    const float4 a = *(const float4*)(x + i);
    const float4 b = *(const float4*)(x + i + 4);
    union { uint4 u4; unsigned short us[8]; } o;
    o.us[0]=f2bf_rne(a.x); o.us[1]=f2bf_rne(a.y); o.us[2]=f2bf_rne(a.z); o.us[3]=f2bf_rne(a.w);
    o.us[4]=f2bf_rne(b.x); o.us[5]=f2bf_rne(b.y); o.us[6]=f2bf_rne(b.z); o.us[7]=f2bf_rne(b.w);
    *(uint4*)(g_xb + i) = o.u4;
}

// ---------------------------------------------------------------------------
// Weight transpose + cast: W fp32 [1024][N] -> dst bf16 [N][1024]
// ---------------------------------------------------------------------------
__global__ __launch_bounds__(256) void transcast_w(
    const float* __restrict__ W, int N, int which)
{
    unsigned short* dst = which ? g_woT : g_wqT;
    __shared__ unsigned short T[64][72];
    const int n0 = blockIdx.x * 64, k0 = blockIdx.y * 64;
    const int tid = threadIdx.x;
    const int r = tid >> 2, c0 = (tid & 3) * 16;

#pragma unroll
    for (int it = 0; it < 4; ++it) {
        const float4 v = *(const float4*)(W + (size_t)(k0 + r)*N + n0 + c0 + it*4);
        T[r][c0 + it*4 + 0] = f2bf_rne(v.x);
        T[r][c0 + it*4 + 1] = f2bf_rne(v.y);
        T[r][c0 + it*4 + 2] = f2bf_rne(v.z);
        T[r][c0 + it*4 + 3] = f2bf_rne(v.w);
    }
    __syncthreads();
    const int nr = tid >> 2, kc0 = (tid & 3) * 16;
#pragma unroll
    for (int it = 0; it < 2; ++it) {
        union { uint4 u4; unsigned short us[8]; } o;
#pragma unroll
        for (int j = 0; j < 8; j++) o.us[j] = T[kc0 + it*8 + j][nr];
        *(uint4*)(dst + (size_t)(n0 + nr)*DMODEL + k0 + kc0 + it*8) = o.u4;
    }
}

// ---------------------------------------------------------------------------
// MFMA GEMM, m97 structure: 128x128 tile, BK=32, global_load_lds width=16
// staging into unpadded lane-contiguous LDS, 16 MFMA + 8 ds_read_b128 per
// wave per K-slab. QKV_MODE=1: A=g_xb, B=g_wqT, epilogue splits Q|K|VT
// (V written transposed, 4 tokens packed per 8B). QKV_MODE=0: A=runtime bf16,
// B=g_woT, fp32 C with bias.
// C/D layout: col=lane&15, row=quad*4+reg. A/B frag [m|n=lane&15][k=quad*8+j].
// ---------------------------------------------------------------------------
template<int QKV_MODE>
__global__ __launch_bounds__(256) void gemm_mfma(
    const void* __restrict__ Av, const float* __restrict__ bias,
    void* __restrict__ C0, void* __restrict__ C1, void* __restrict__ C2)
{
    const unsigned short* A  = QKV_MODE ? g_xb : (const unsigned short*)Av;
    const unsigned short* BT = QKV_MODE ? g_wqT : g_woT;
    __shared__ alignas(16) unsigned short As[128*32];   // [m][k] unpadded
    __shared__ alignas(16) unsigned short Bs[128*32];   // [n][k] unpadded

    const int tid = threadIdx.x;
    const int bm = blockIdx.y, bn = blockIdx.x;
    const int w = tid >> 6, lane = tid & 63;
    const int m16 = lane & 15, quad = lane >> 4;
    const int m0 = (w & 1) * 64, n0w = (w >> 1) * 64;

    // staging: wave w covers rows [w*32, w*32+32), lane i -> row +i/4, col 8*(i&3)
    const int lrow  = lane >> 2;
    const int lcol  = (lane & 3) * 8;
    const unsigned short* aG = A  + (size_t)(bm*128 + w*32 + lrow)*DMODEL + lcol;
    const unsigned short* bG = BT + (size_t)(bn*128 + w*32 + lrow)*DMODEL + lcol;
    char* asL = (char*)As + w*2048;
    char* bsL = (char*)Bs + w*2048;

    floatx4 acc[4][4];
#pragma unroll
    for (int i = 0; i < 4; i++)
#pragma unroll
        for (int j = 0; j < 4; j++) { acc[i][j][0]=0.f; acc[i][j][1]=0.f; acc[i][j][2]=0.f; acc[i][j][3]=0.f; }

    for (int k0 = 0; k0 < DMODEL; k0 += 32) {
        __syncthreads();                       // previous slab's readers done
        gload_lds16(aG + k0,              asL);
        gload_lds16(aG + 16*DMODEL + k0,  asL + 1024);
        gload_lds16(bG + k0,              bsL);
        gload_lds16(bG + 16*DMODEL + k0,  bsL + 1024);
        __syncthreads();                       // drains vmcnt -> LDS ready

        short8 af[4], bf4[4];
#pragma unroll
        for (int i = 0; i < 4; ++i) af[i]  = *(const short8*)&As[(m0 + i*16 + m16)*32 + quad*8];
#pragma unroll
        for (int j = 0; j < 4; ++j) bf4[j] = *(const short8*)&Bs[(n0w + j*16 + m16)*32 + quad*8];
#pragma unroll
        for (int i = 0; i < 4; ++i)
#pragma unroll
            for (int j = 0; j < 4; ++j)
                acc[i][j] = __builtin_amdgcn_mfma_f32_16x16x32_bf16(af[i], bf4[j], acc[i][j], 0, 0, 0);
    }

    const int gcolb = bn*128;
    float bv[4];
#pragma unroll
    for (int j = 0; j < 4; ++j) bv[j] = bias[gcolb + n0w + j*16 + m16];

    if (QKV_MODE) {
        const int seg = gcolb >> 10;           // 0=Q, 1=K, 2=V(transposed)
        if (seg < 2) {
            bf16* Cout = (bf16*)(seg ? C1 : C0);
#pragma unroll
            for (int i = 0; i < 4; ++i)
#pragma unroll
                for (int r = 0; r < 4; ++r) {
                    const int gm = bm*128 + m0 + i*16 + quad*4 + r;
#pragma unroll
                    for (int j = 0; j < 4; ++j) {
                        const int cc = (gcolb + n0w + j*16 + m16) & 1023;
                        Cout[(size_t)gm*DMODEL + cc] = __float2bfloat16(acc[i][j][r] + bv[j]);
                    }
                }
        } else {
            // V: write transposed VT[((b*16+h)*64+d)*2048 + t], 4 tokens/8B
            bf16* VT = (bf16*)C2;
#pragma unroll
            for (int i = 0; i < 4; ++i) {
                const int gm0 = bm*128 + m0 + i*16 + quad*4;
                const int bb = gm0 >> 11, t0 = gm0 & 2047;
#pragma unroll
                for (int j = 0; j < 4; ++j) {
                    const int cv = (gcolb & 1023) + n0w + j*16 + m16;
                    const int hh = cv >> 6, dd = cv & 63;
                    union { unsigned long long u8; unsigned short us[4]; } o;
#pragma unroll
                    for (int r = 0; r < 4; ++r) o.us[r] = f2bf_rne(acc[i][j][r] + bv[j]);
                    *(unsigned long long*)(VT + ((size_t)((bb*NHEADS + hh)*DHEAD + dd))*SEQ + t0) = o.u8;
                }
            }
        }
    } else {
        float* Cout = (float*)C0;
#pragma unroll
        for (int i = 0; i < 4; ++i)
#pragma unroll
            for (int r = 0; r < 4; ++r) {
                const int gm = bm*128 + m0 + i*16 + quad*4 + r;
#pragma unroll
                for (int j = 0; j < 4; ++j) {
                    const int cc = (gcolb + n0w + j*16 + m16) & 1023;
                    Cout[(size_t)gm*DMODEL + cc] = acc[i][j][r] + bv[j];
                }
            }
    }
}

// ---------------------------------------------------------------------------
// MFMA flash attention v2 (unchanged from round 8 — passed, 134 us)
// ---------------------------------------------------------------------------
__global__ __launch_bounds__(256, 2) void attn_mfma2(
    const bf16* __restrict__ Qg, const bf16* __restrict__ Kg,
    const bf16* __restrict__ VTg, bf16* __restrict__ Og)
{
    __shared__ alignas(16) unsigned short Kt[2][64][72];
    __shared__ alignas(16) unsigned short Vt[2][64][72];
    __shared__ alignas(16) unsigned short Ps[4][32][72];

    const int x = blockIdx.x;
    const int b = x >> 7, h = (x >> 3) & 15, p = x & 7;
    const int tid = threadIdx.x;
    const int w = tid >> 6, lane = tid & 63;
    const int m16 = lane & 15, quad = lane >> 4;
    const int sr = tid >> 2, sc0 = (tid & 3) * 8;
    const size_t bh = (size_t)(b*NHEADS + h);

    for (int seg = 0; seg < 2; ++seg) {
        const int qt  = seg ? (15 - p) : p;
        const int nkt = 2*qt + 2;
        const int qrow0 = qt*128 + w*32;

        short8 qf[2][2];
#pragma unroll
        for (int i = 0; i < 2; ++i)
#pragma unroll
            for (int c = 0; c < 2; ++c)
                qf[i][c] = *(const short8*)(Qg + (size_t)(b*SEQ + qrow0 + i*16 + m16)*DMODEL
                                            + h*DHEAD + c*32 + quad*8);

        floatx4 of[2][4];
        float mrow[2][4], lrow[2][4];
#pragma unroll
        for (int i = 0; i < 2; ++i) {
#pragma unroll
            for (int nt = 0; nt < 4; ++nt) { of[i][nt][0]=0.f; of[i][nt][1]=0.f; of[i][nt][2]=0.f; of[i][nt][3]=0.f; }
#pragma unroll
            for (int r = 0; r < 4; ++r) { mrow[i][r] = NEG_BIG; lrow[i][r] = 0.f; }
        }

        {
            const bf16* kp = Kg  + (size_t)(b*SEQ + sr)*DMODEL + h*DHEAD + sc0;
            const bf16* vp = VTg + (bh*DHEAD + sr)*SEQ + sc0;
            const uint4 a0 = *(const uint4*)kp, a1 = *(const uint4*)(kp + 32);
            const uint4 b0 = *(const uint4*)vp, b1 = *(const uint4*)(vp + 32);
            __syncthreads();
            *(uint4*)&Kt[0][sr][sc0]      = a0;
            *(uint4*)&Kt[0][sr][sc0 + 32] = a1;
            *(uint4*)&Vt[0][sr][sc0]      = b0;
            *(uint4*)&Vt[0][sr][sc0 + 32] = b1;
            __syncthreads();
        }

        for (int kt = 0; kt < nkt; ++kt) {
            const int buf = kt & 1;
            const int k064 = kt * 64;
            const bool pre = (kt + 1 < nkt);
            uint4 kr0, kr1, vr0, vr1;
            if (pre) {
                const bf16* kp = Kg  + (size_t)(b*SEQ + k064 + 64 + sr)*DMODEL + h*DHEAD + sc0;
                const bf16* vp = VTg + (bh*DHEAD + sr)*SEQ + k064 + 64 + sc0;
                kr0 = *(const uint4*)kp; kr1 = *(const uint4*)(kp + 32);
                vr0 = *(const uint4*)vp; vr1 = *(const uint4*)(vp + 32);
            }

            floatx4 sf[2][4];
#pragma unroll
            for (int t4 = 0; t4 < 4; ++t4) {
                const short8 kf0 = *(const short8*)&Kt[buf][t4*16 + m16][quad*8];
                const short8 kf1 = *(const short8*)&Kt[buf][t4*16 + m16][32 + quad*8];
#pragma unroll
                for (int i = 0; i < 2; ++i) {
                    floatx4 a; a[0]=0.f; a[1]=0.f; a[2]=0.f; a[3]=0.f;
                    a = __builtin_amdgcn_mfma_f32_16x16x32_bf16(qf[i][0], kf0, a, 0, 0, 0);
                    a = __builtin_amdgcn_mfma_f32_16x16x32_bf16(qf[i][1], kf1, a, 0, 0, 0);
                    sf[i][t4] = a;
                }
            }

            const bool need_mask = (kt >= 2*qt);
#pragma unroll
            for (int i = 0; i < 2; ++i) {
                float mx[4];
#pragma unroll
                for (int r = 0; r < 4; ++r) {
                    const int qg = qrow0 + i*16 + quad*4 + r;
                    float vm = NEG_BIG;
#pragma unroll
                    for (int t4 = 0; t4 < 4; ++t4) {
                        float s = sf[i][t4][r] * 0.125f;
                        if (need_mask && (k064 + t4*16 + m16 > qg)) s = NEG_BIG;
                        sf[i][t4][r] = s;
                        vm = fmaxf(vm, s);
                    }
                    mx[r] = vm;
                }
#pragma unroll
                for (int off = 1; off < 16; off <<= 1)
#pragma unroll
                    for (int r = 0; r < 4; ++r) mx[r] = fmaxf(mx[r], __shfl_xor(mx[r], off));

                float rs[4], alpha[4];
#pragma unroll
                for (int r = 0; r < 4; ++r) {
                    const float mnew = fmaxf(mrow[i][r], mx[r]);
                    alpha[r] = __expf(mrow[i][r] - mnew);
                    mrow[i][r] = mnew;
                    float sum = 0.f;
#pragma unroll
                    for (int t4 = 0; t4 < 4; ++t4) {
                        const float pv = __expf(sf[i][t4][r] - mnew);
                        sf[i][t4][r] = pv;
                        sum += pv;
                    }
                    rs[r] = sum;
                }
#pragma unroll
                for (int off = 1; off < 16; off <<= 1)
#pragma unroll
                    for (int r = 0; r < 4; ++r) rs[r] += __shfl_xor(rs[r], off);
#pragma unroll
                for (int r = 0; r < 4; ++r) lrow[i][r] = lrow[i][r]*alpha[r] + rs[r];
#pragma unroll
                for (int nt = 0; nt < 4; ++nt)
#pragma unroll
                    for (int r = 0; r < 4; ++r) of[i][nt][r] *= alpha[r];
#pragma unroll
                for (int t4 = 0; t4 < 4; ++t4)
#pragma unroll
                    for (int r = 0; r < 4; ++r)
                        Ps[w][i*16 + quad*4 + r][t4*16 + m16] = f2bf_rne(sf[i][t4][r]);
            }

            short8 pf[2][2];
#pragma unroll
            for (int i = 0; i < 2; ++i)
#pragma unroll
                for (int c = 0; c < 2; ++c)
                    pf[i][c] = *(const short8*)&Ps[w][i*16 + m16][c*32 + quad*8];
#pragma unroll
            for (int nt = 0; nt < 4; ++nt) {
                const short8 vf0 = *(const short8*)&Vt[buf][nt*16 + m16][quad*8];
                const short8 vf1 = *(const short8*)&Vt[buf][nt*16 + m16][32 + quad*8];
#pragma unroll
                for (int i = 0; i < 2; ++i) {
                    of[i][nt] = __builtin_amdgcn_mfma_f32_16x16x32_bf16(pf[i][0], vf0, of[i][nt], 0, 0, 0);
                    of[i][nt] = __builtin_amdgcn_mfma_f32_16x16x32_bf16(pf[i][1], vf1, of[i][nt], 0, 0, 0);
                }
            }

            if (pre) {
                *(uint4*)&Kt[buf^1][sr][sc0]      = kr0;
                *(uint4*)&Kt[buf^1][sr][sc0 + 32] = kr1;
                *(uint4*)&Vt[buf^1][sr][sc0]      = vr0;
                *(uint4*)&Vt[buf^1][sr][sc0 + 32] = vr1;
            }
            __syncthreads();
        }

#pragma unroll
        for (int i = 0; i < 2; ++i) {
            float rl[4];
#pragma unroll
            for (int r = 0; r < 4; ++r) rl[r] = 1.f / fmaxf(lrow[i][r], 1e-20f);
#pragma unroll
            for (int nt = 0; nt < 4; ++nt)
#pragma unroll
                for (int r = 0; r < 4; ++r) {
                    const int row = qrow0 + i*16 + quad*4 + r;
                    Og[(size_t)(b*SEQ + row)*DMODEL + h*DHEAD + nt*16 + m16] =
                        __float2bfloat16(of[i][nt][r] * rl[r]);
                }
        }
    }
}

__global__ void diag_fill(float* out, int n, float val) {
    int i = blockIdx.x*blockDim.x + threadIdx.x;
    if (i < n) out[i] = val;
}

// ---------------------------------------------------------------------------
extern "C" void kernel_launch(void* const* d_in, const int* in_sizes, int n_in,
                              void* d_out, int out_size, void* d_ws, size_t ws_size,
                              hipStream_t stream) {
    const float* x     = (const float*)d_in[0];
    const float* W_qkv = (const float*)d_in[1];
    const float* b_qkv = (const float*)d_in[2];
    const float* W_out = (const float*)d_in[3];
    const float* b_out = (const float*)d_in[4];

    if (ws_size < WS_NEED) {
        const float val = 100.f + (float)(ws_size >> 20);
        diag_fill<<<(out_size + 255)/256, 256, 0, stream>>>((float*)d_out, out_size, val);
        return;
    }

    bf16* Qb  = (bf16*)d_out;                                // d_out lo: Q
    bf16* VTb = (bf16*)d_out + (size_t)MROWS*DMODEL;         // d_out hi: VT
    bf16* Kb  = (bf16*)d_ws;                                 // ws lo: K
    bf16* Ob  = (bf16*)d_ws + (size_t)MROWS*DMODEL;          // ws hi: O

    // 0) casts
    cast_x<<<MROWS*DMODEL/2048, 256, 0, stream>>>(x);
    {
        dim3 gq(QKV_N/64, DMODEL/64);
        transcast_w<<<gq, 256, 0, stream>>>(W_qkv, QKV_N, 0);
        dim3 go(DMODEL/64, DMODEL/64);
        transcast_w<<<go, 256, 0, stream>>>(W_out, DMODEL, 1);
    }
    // 1) fused QKV projection; V written pre-transposed into VT
    {
        dim3 g(QKV_N/128, MROWS/128);
        gemm_mfma<1><<<g, 256, 0, stream>>>(nullptr, b_qkv, Qb, Kb, VTb);
    }
    // 2) flash attention: O -> ws hi
    {
        attn_mfma2<<<512, 256, 0, stream>>>(Qb, Kb, VTb, Ob);
    }
    // 3) output projection: O bf16 -> fp32 d_out (Q/VT dead)
    {
        dim3 g(DMODEL/128, MROWS/128);
        gemm_mfma<0><<<g, 256, 0, stream>>>(Ob, b_out, d_out, nullptr, nullptr);
    }
}

// Round 10
// 306.678 us; speedup vs baseline: 14.4253x; 1.1114x over previous
//
#include <hip/hip_runtime.h>
#include <hip/hip_bf16.h>

#define BATCH   4
#define SEQ     2048
#define DMODEL  1024
#define NHEADS  16
#define DHEAD   64
#define MROWS   (BATCH*SEQ)        // 8192
#define QKV_N   (3*DMODEL)         // 3072
#define NEG_BIG (-1.0e30f)
#define WS_NEED ((size_t)MROWS * 2*DMODEL * sizeof(__hip_bfloat16))  // 33,554,432
#define SCALE_Q 0.18033688011112042f   // 0.125 * log2(e); folded into Q at projection

using bf16 = __hip_bfloat16;
typedef __attribute__((ext_vector_type(8))) short short8;
typedef __attribute__((ext_vector_type(4))) float floatx4;

// Static device buffers (module BSS; no hipMalloc)
__device__ __align__(16) unsigned short g_wqT[QKV_N * DMODEL];   // W_qkv^T bf16
__device__ __align__(16) unsigned short g_woT[DMODEL * DMODEL];  // W_out^T bf16
__device__ __align__(16) unsigned short g_xb [MROWS * DMODEL];   // x bf16

__device__ __forceinline__ unsigned short f2bf_rne(float f) {
    union { bf16 b; unsigned short u; } t;
    t.b = __float2bfloat16(f);
    return t.u;
}

// async global->LDS, 16B per lane; LDS dest = wave-uniform base + lane*16
__device__ __forceinline__ void gload_lds16(const void* g, void* l) {
    __builtin_amdgcn_global_load_lds(
        (const __attribute__((address_space(1))) unsigned*)g,
        (__attribute__((address_space(3))) unsigned*)l, 16, 0, 0);
}

// ---------------------------------------------------------------------------
// x fp32 -> bf16
// ---------------------------------------------------------------------------
__global__ __launch_bounds__(256) void cast_x(const float* __restrict__ x) {
    const size_t i = ((size_t)blockIdx.x*256 + threadIdx.x)*8;
    const float4 a = *(const float4*)(x + i);
    const float4 b = *(const float4*)(x + i + 4);
    union { uint4 u4; unsigned short us[8]; } o;
    o.us[0]=f2bf_rne(a.x); o.us[1]=f2bf_rne(a.y); o.us[2]=f2bf_rne(a.z); o.us[3]=f2bf_rne(a.w);
    o.us[4]=f2bf_rne(b.x); o.us[5]=f2bf_rne(b.y); o.us[6]=f2bf_rne(b.z); o.us[7]=f2bf_rne(b.w);
    *(uint4*)(g_xb + i) = o.u4;
}

// ---------------------------------------------------------------------------
// Weight transpose + cast: W fp32 [1024][N] -> dst bf16 [N][1024]
// ---------------------------------------------------------------------------
__global__ __launch_bounds__(256) void transcast_w(
    const float* __restrict__ W, int N, int which)
{
    unsigned short* dst = which ? g_woT : g_wqT;
    __shared__ unsigned short T[64][72];
    const int n0 = blockIdx.x * 64, k0 = blockIdx.y * 64;
    const int tid = threadIdx.x;
    const int r = tid >> 2, c0 = (tid & 3) * 16;

#pragma unroll
    for (int it = 0; it < 4; ++it) {
        const float4 v = *(const float4*)(W + (size_t)(k0 + r)*N + n0 + c0 + it*4);
        T[r][c0 + it*4 + 0] = f2bf_rne(v.x);
        T[r][c0 + it*4 + 1] = f2bf_rne(v.y);
        T[r][c0 + it*4 + 2] = f2bf_rne(v.z);
        T[r][c0 + it*4 + 3] = f2bf_rne(v.w);
    }
    __syncthreads();
    const int nr = tid >> 2, kc0 = (tid & 3) * 16;
#pragma unroll
    for (int it = 0; it < 2; ++it) {
        union { uint4 u4; unsigned short us[8]; } o;
#pragma unroll
        for (int j = 0; j < 8; j++) o.us[j] = T[kc0 + it*8 + j][nr];
        *(uint4*)(dst + (size_t)(n0 + nr)*DMODEL + k0 + kc0 + it*8) = o.u4;
    }
}

// ---------------------------------------------------------------------------
// MFMA GEMM (m97 staging). QKV_MODE=1: A=g_xb, B=g_wqT, epilogue splits
// Q|K|VT; Q is pre-scaled by SCALE_Q (softmax scale folded in, base-2 units);
// V written transposed. QKV_MODE=0: A=runtime bf16, B=g_woT, fp32 C + bias.
// ---------------------------------------------------------------------------
template<int QKV_MODE>
__global__ __launch_bounds__(256) void gemm_mfma(
    const void* __restrict__ Av, const float* __restrict__ bias,
    void* __restrict__ C0, void* __restrict__ C1, void* __restrict__ C2)
{
    const unsigned short* A  = QKV_MODE ? g_xb : (const unsigned short*)Av;
    const unsigned short* BT = QKV_MODE ? g_wqT : g_woT;
    __shared__ alignas(16) unsigned short As[128*32];   // [m][k] unpadded
    __shared__ alignas(16) unsigned short Bs[128*32];   // [n][k] unpadded

    const int tid = threadIdx.x;
    const int bm = blockIdx.y, bn = blockIdx.x;
    const int w = tid >> 6, lane = tid & 63;
    const int m16 = lane & 15, quad = lane >> 4;
    const int m0 = (w & 1) * 64, n0w = (w >> 1) * 64;

    const int lrow  = lane >> 2;
    const int lcol  = (lane & 3) * 8;
    const unsigned short* aG = A  + (size_t)(bm*128 + w*32 + lrow)*DMODEL + lcol;
    const unsigned short* bG = BT + (size_t)(bn*128 + w*32 + lrow)*DMODEL + lcol;
    char* asL = (char*)As + w*2048;
    char* bsL = (char*)Bs + w*2048;

    floatx4 acc[4][4];
#pragma unroll
    for (int i = 0; i < 4; i++)
#pragma unroll
        for (int j = 0; j < 4; j++) { acc[i][j][0]=0.f; acc[i][j][1]=0.f; acc[i][j][2]=0.f; acc[i][j][3]=0.f; }

    for (int k0 = 0; k0 < DMODEL; k0 += 32) {
        __syncthreads();
        gload_lds16(aG + k0,              asL);
        gload_lds16(aG + 16*DMODEL + k0,  asL + 1024);
        gload_lds16(bG + k0,              bsL);
        gload_lds16(bG + 16*DMODEL + k0,  bsL + 1024);
        __syncthreads();

        short8 af[4], bf4[4];
#pragma unroll
        for (int i = 0; i < 4; ++i) af[i]  = *(const short8*)&As[(m0 + i*16 + m16)*32 + quad*8];
#pragma unroll
        for (int j = 0; j < 4; ++j) bf4[j] = *(const short8*)&Bs[(n0w + j*16 + m16)*32 + quad*8];
#pragma unroll
        for (int i = 0; i < 4; ++i)
#pragma unroll
            for (int j = 0; j < 4; ++j)
                acc[i][j] = __builtin_amdgcn_mfma_f32_16x16x32_bf16(af[i], bf4[j], acc[i][j], 0, 0, 0);
    }

    const int gcolb = bn*128;
    float bv[4];
#pragma unroll
    for (int j = 0; j < 4; ++j) bv[j] = bias[gcolb + n0w + j*16 + m16];

    if (QKV_MODE) {
        const int seg = gcolb >> 10;           // 0=Q(scaled), 1=K, 2=V(transposed)
        if (seg < 2) {
            bf16* Cout = (bf16*)(seg ? C1 : C0);
            const float sc = seg ? 1.0f : SCALE_Q;
#pragma unroll
            for (int i = 0; i < 4; ++i)
#pragma unroll
                for (int r = 0; r < 4; ++r) {
                    const int gm = bm*128 + m0 + i*16 + quad*4 + r;
#pragma unroll
                    for (int j = 0; j < 4; ++j) {
                        const int cc = (gcolb + n0w + j*16 + m16) & 1023;
                        Cout[(size_t)gm*DMODEL + cc] = __float2bfloat16((acc[i][j][r] + bv[j]) * sc);
                    }
                }
        } else {
            bf16* VT = (bf16*)C2;
#pragma unroll
            for (int i = 0; i < 4; ++i) {
                const int gm0 = bm*128 + m0 + i*16 + quad*4;
                const int bb = gm0 >> 11, t0 = gm0 & 2047;
#pragma unroll
                for (int j = 0; j < 4; ++j) {
                    const int cv = (gcolb & 1023) + n0w + j*16 + m16;
                    const int hh = cv >> 6, dd = cv & 63;
                    union { unsigned long long u8; unsigned short us[4]; } o;
#pragma unroll
                    for (int r = 0; r < 4; ++r) o.us[r] = f2bf_rne(acc[i][j][r] + bv[j]);
                    *(unsigned long long*)(VT + ((size_t)((bb*NHEADS + hh)*DHEAD + dd))*SEQ + t0) = o.u8;
                }
            }
        }
    } else {
        float* Cout = (float*)C0;
#pragma unroll
        for (int i = 0; i < 4; ++i)
#pragma unroll
            for (int r = 0; r < 4; ++r) {
                const int gm = bm*128 + m0 + i*16 + quad*4 + r;
#pragma unroll
                for (int j = 0; j < 4; ++j) {
                    const int cc = (gcolb + n0w + j*16 + m16) & 1023;
                    Cout[(size_t)gm*DMODEL + cc] = acc[i][j][r] + bv[j];
                }
            }
    }
}

// ---------------------------------------------------------------------------
// MFMA flash attention v3 — transposed formulation. S^T = K·Q^T and
// O^T = V^T·P^T via operand-swapped MFMAs (A/B frags share layout, so the
// swap is free). Each lane owns ONE q-column per i-group: softmax reduction
// = 15 in-reg ops + 2 shuffle rounds; m/l/alpha scalar per lane; P^T and O
// stored as packed b64 (4 consecutive keys/dims per reg quad). Q arrives
// pre-scaled by 0.125*log2(e) -> exp2-based online softmax.
// Block = paired q-tiles {p, 15-p} (uniform 34 iters); dbuf K/V tiles.
// ---------------------------------------------------------------------------
__global__ __launch_bounds__(256, 2) void attn_mfma3(
    const bf16* __restrict__ Qg, const bf16* __restrict__ Kg,
    const bf16* __restrict__ VTg, bf16* __restrict__ Og)
{
    __shared__ alignas(16) unsigned short Kt[2][64][72];   // [buf][key][d]
    __shared__ alignas(16) unsigned short Vt[2][64][72];   // [buf][d][key]
    __shared__ alignas(16) unsigned short Ps[4][32][72];   // [wave][q][key] = P^T cols

    const int x = blockIdx.x;
    const int b = x >> 7, h = (x >> 3) & 15, p = x & 7;
    const int tid = threadIdx.x;
    const int w = tid >> 6, lane = tid & 63;
    const int m16 = lane & 15, quad = lane >> 4;
    const int sr = tid >> 2, sc0 = (tid & 3) * 8;
    const size_t bh = (size_t)(b*NHEADS + h);

    for (int seg = 0; seg < 2; ++seg) {
        const int qt  = seg ? (15 - p) : p;
        const int nkt = 2*qt + 2;
        const int qrow0 = qt*128 + w*32;

        short8 qf[2][2];
#pragma unroll
        for (int i = 0; i < 2; ++i)
#pragma unroll
            for (int c = 0; c < 2; ++c)
                qf[i][c] = *(const short8*)(Qg + (size_t)(b*SEQ + qrow0 + i*16 + m16)*DMODEL
                                            + h*DHEAD + c*32 + quad*8);

        floatx4 of[2][4];
        float mrow[2], lrow[2];
#pragma unroll
        for (int i = 0; i < 2; ++i) {
            mrow[i] = NEG_BIG; lrow[i] = 0.f;
#pragma unroll
            for (int nt = 0; nt < 4; ++nt) { of[i][nt][0]=0.f; of[i][nt][1]=0.f; of[i][nt][2]=0.f; of[i][nt][3]=0.f; }
        }

        // ---- stage tile 0 into buf 0
        {
            const bf16* kp = Kg  + (size_t)(b*SEQ + sr)*DMODEL + h*DHEAD + sc0;
            const bf16* vp = VTg + (bh*DHEAD + sr)*SEQ + sc0;
            const uint4 a0 = *(const uint4*)kp, a1 = *(const uint4*)(kp + 32);
            const uint4 b0 = *(const uint4*)vp, b1 = *(const uint4*)(vp + 32);
            __syncthreads();
            *(uint4*)&Kt[0][sr][sc0]      = a0;
            *(uint4*)&Kt[0][sr][sc0 + 32] = a1;
            *(uint4*)&Vt[0][sr][sc0]      = b0;
            *(uint4*)&Vt[0][sr][sc0 + 32] = b1;
            __syncthreads();
        }

        for (int kt = 0; kt < nkt; ++kt) {
            const int buf = kt & 1;
            const int k064 = kt * 64;
            const bool pre = (kt + 1 < nkt);
            uint4 kr0, kr1, vr0, vr1;
            if (pre) {
                const bf16* kp = Kg  + (size_t)(b*SEQ + k064 + 64 + sr)*DMODEL + h*DHEAD + sc0;
                const bf16* vp = VTg + (bh*DHEAD + sr)*SEQ + k064 + 64 + sc0;
                kr0 = *(const uint4*)kp; kr1 = *(const uint4*)(kp + 32);
                vr0 = *(const uint4*)vp; vr1 = *(const uint4*)(vp + 32);
            }

            // ---- S^T = K Q^T (16 MFMA): rows=key(quad*4+r, t4), cols=q(m16)
            floatx4 sf[2][4];
#pragma unroll
            for (int t4 = 0; t4 < 4; ++t4) {
                const short8 kf0 = *(const short8*)&Kt[buf][t4*16 + m16][quad*8];
                const short8 kf1 = *(const short8*)&Kt[buf][t4*16 + m16][32 + quad*8];
#pragma unroll
                for (int i = 0; i < 2; ++i) {
                    floatx4 a; a[0]=0.f; a[1]=0.f; a[2]=0.f; a[3]=0.f;
                    a = __builtin_amdgcn_mfma_f32_16x16x32_bf16(kf0, qf[i][0], a, 0, 0, 0);
                    a = __builtin_amdgcn_mfma_f32_16x16x32_bf16(kf1, qf[i][1], a, 0, 0, 0);
                    sf[i][t4] = a;
                }
            }

            // ---- online softmax (per lane = per q-column)
            const bool need_mask = (k064 + 63 > qrow0);
#pragma unroll
            for (int i = 0; i < 2; ++i) {
                if (need_mask) {
                    const int qg = qrow0 + i*16 + m16;
#pragma unroll
                    for (int t4 = 0; t4 < 4; ++t4)
#pragma unroll
                        for (int r = 0; r < 4; ++r)
                            if (k064 + t4*16 + quad*4 + r > qg) sf[i][t4][r] = NEG_BIG;
                }
                float mx = sf[i][0][0];
#pragma unroll
                for (int t4 = 0; t4 < 4; ++t4)
#pragma unroll
                    for (int r = 0; r < 4; ++r) mx = fmaxf(mx, sf[i][t4][r]);
                mx = fmaxf(mx, __shfl_xor(mx, 16));
                mx = fmaxf(mx, __shfl_xor(mx, 32));

                const float mnew  = fmaxf(mrow[i], mx);
                const float alpha = exp2f(mrow[i] - mnew);
                mrow[i] = mnew;

                float rs = 0.f;
#pragma unroll
                for (int t4 = 0; t4 < 4; ++t4) {
#pragma unroll
                    for (int r = 0; r < 4; ++r) {
                        const float pv = exp2f(sf[i][t4][r] - mnew);
                        sf[i][t4][r] = pv;
                        rs += pv;
                    }
                }
                rs += __shfl_xor(rs, 16);
                rs += __shfl_xor(rs, 32);
                lrow[i] = lrow[i]*alpha + rs;
#pragma unroll
                for (int nt = 0; nt < 4; ++nt)
#pragma unroll
                    for (int r = 0; r < 4; ++r) of[i][nt][r] *= alpha;

                // P^T -> LDS: 4 consecutive keys per b64 store
#pragma unroll
                for (int t4 = 0; t4 < 4; ++t4) {
                    union { unsigned long long u8; unsigned short us[4]; } o;
#pragma unroll
                    for (int r = 0; r < 4; ++r) o.us[r] = f2bf_rne(sf[i][t4][r]);
                    *(unsigned long long*)&Ps[w][i*16 + m16][t4*16 + quad*4] = o.u8;
                }
            }

            // ---- O^T += V^T P^T (16 MFMA); Ps wave-local
            short8 pf[2][2];
#pragma unroll
            for (int i = 0; i < 2; ++i)
#pragma unroll
                for (int c = 0; c < 2; ++c)
                    pf[i][c] = *(const short8*)&Ps[w][i*16 + m16][c*32 + quad*8];
#pragma unroll
            for (int nt = 0; nt < 4; ++nt) {
                const short8 vf0 = *(const short8*)&Vt[buf][nt*16 + m16][quad*8];
                const short8 vf1 = *(const short8*)&Vt[buf][nt*16 + m16][32 + quad*8];
#pragma unroll
                for (int i = 0; i < 2; ++i) {
                    of[i][nt] = __builtin_amdgcn_mfma_f32_16x16x32_bf16(vf0, pf[i][0], of[i][nt], 0, 0, 0);
                    of[i][nt] = __builtin_amdgcn_mfma_f32_16x16x32_bf16(vf1, pf[i][1], of[i][nt], 0, 0, 0);
                }
            }

            if (pre) {
                *(uint4*)&Kt[buf^1][sr][sc0]      = kr0;
                *(uint4*)&Kt[buf^1][sr][sc0 + 32] = kr1;
                *(uint4*)&Vt[buf^1][sr][sc0]      = vr0;
                *(uint4*)&Vt[buf^1][sr][sc0 + 32] = vr1;
            }
            __syncthreads();
        }

        // ---- normalize + store O: lane owns row q, dims nt*16+quad*4+{0..3}
#pragma unroll
        for (int i = 0; i < 2; ++i) {
            const float rl = 1.f / fmaxf(lrow[i], 1e-20f);
            const size_t rowbase = (size_t)(b*SEQ + qrow0 + i*16 + m16)*DMODEL + h*DHEAD;
#pragma unroll
            for (int nt = 0; nt < 4; ++nt) {
                union { unsigned long long u8; unsigned short us[4]; } o;
#pragma unroll
                for (int r = 0; r < 4; ++r) o.us[r] = f2bf_rne(of[i][nt][r] * rl);
                *(unsigned long long*)(Og + rowbase + nt*16 + quad*4) = o.u8;
            }
        }
    }
}

__global__ void diag_fill(float* out, int n, float val) {
    int i = blockIdx.x*blockDim.x + threadIdx.x;
    if (i < n) out[i] = val;
}

// ---------------------------------------------------------------------------
extern "C" void kernel_launch(void* const* d_in, const int* in_sizes, int n_in,
                              void* d_out, int out_size, void* d_ws, size_t ws_size,
                              hipStream_t stream) {
    const float* x     = (const float*)d_in[0];
    const float* W_qkv = (const float*)d_in[1];
    const float* b_qkv = (const float*)d_in[2];
    const float* W_out = (const float*)d_in[3];
    const float* b_out = (const float*)d_in[4];

    if (ws_size < WS_NEED) {
        const float val = 100.f + (float)(ws_size >> 20);
        diag_fill<<<(out_size + 255)/256, 256, 0, stream>>>((float*)d_out, out_size, val);
        return;
    }

    bf16* Qb  = (bf16*)d_out;                                // d_out lo: Q (pre-scaled)
    bf16* VTb = (bf16*)d_out + (size_t)MROWS*DMODEL;         // d_out hi: VT
    bf16* Kb  = (bf16*)d_ws;                                 // ws lo: K
    bf16* Ob  = (bf16*)d_ws + (size_t)MROWS*DMODEL;          // ws hi: O

    // 0) casts
    cast_x<<<MROWS*DMODEL/2048, 256, 0, stream>>>(x);
    {
        dim3 gq(QKV_N/64, DMODEL/64);
        transcast_w<<<gq, 256, 0, stream>>>(W_qkv, QKV_N, 0);
        dim3 go(DMODEL/64, DMODEL/64);
        transcast_w<<<go, 256, 0, stream>>>(W_out, DMODEL, 1);
    }
    // 1) fused QKV projection; Q pre-scaled; V pre-transposed
    {
        dim3 g(QKV_N/128, MROWS/128);
        gemm_mfma<1><<<g, 256, 0, stream>>>(nullptr, b_qkv, Qb, Kb, VTb);
    }
    // 2) flash attention v3 (transposed MFMA formulation)
    {
        attn_mfma3<<<512, 256, 0, stream>>>(Qb, Kb, VTb, Ob);
    }
    // 3) output projection: O bf16 -> fp32 d_out (Q/VT dead)
    {
        dim3 g(DMODEL/128, MROWS/128);
        gemm_mfma<0><<<g, 256, 0, stream>>>(Ob, b_out, d_out, nullptr, nullptr);
    }
}